// Round 7
// baseline (310.440 us; speedup 1.0000x reference)
//
#include <hip/hip_runtime.h>

#define N_NODES 20000
#define N_EDGES 320000
#define NBATCH  128

__device__ __forceinline__ float lrelu(float v) { return v > 0.f ? v : 0.2f * v; }

// ---------------------------------------------------------------- h0 = relu(x@W0+b0); also zero deg
__global__ void k_h0(const float* __restrict__ x, const float* __restrict__ W0,
                     const float* __restrict__ b0, float* __restrict__ h0,
                     int* __restrict__ deg, int n) {
    __shared__ float ws[25 * 64];
    __shared__ float bs[64];
    __shared__ float xs[100];
    int t = threadIdx.x;
    int gid = blockIdx.x * 256 + t;
    if (gid < n) deg[gid] = 0;
    for (int i = t; i < 25 * 64; i += 256) ws[i] = W0[i];
    if (t < 64) bs[t] = b0[t];
    int nb = blockIdx.x * 4;
    if (t < 100 && nb * 25 + t < n * 25) xs[t] = x[(size_t)nb * 25 + t];
    __syncthreads();
    int node = nb + (t >> 6);
    int c = t & 63;
    if (node >= n) return;
    float s = bs[c];
    const float* xr = xs + (t >> 6) * 25;
    #pragma unroll
    for (int k = 0; k < 25; k++) s += xr[k] * ws[k * 64 + c];
    h0[(size_t)node * 64 + c] = fmaxf(s, 0.f);
}

// ---------------------------------------------------------------- merged tiny setup: vsd + segment bounds
__global__ void k_small(const float* __restrict__ Wg, const float* __restrict__ att_s,
                        const float* __restrict__ att_d, float* __restrict__ vsd,
                        const int* __restrict__ batch, int* __restrict__ segst, int n, int b) {
    int t = threadIdx.x;
    if (blockIdx.x == 0) {
        int k = t >> 3, h = t & 7;
        const float* wrow = Wg + (size_t)k * 512 + h * 64;
        float s1 = 0.f, s2 = 0.f;
        #pragma unroll 8
        for (int c = 0; c < 64; c++) {
            float w = wrow[c];
            s1 += w * att_s[h * 64 + c];
            s2 += w * att_d[h * 64 + c];
        }
        vsd[k * 16 + h] = s1;
        vsd[k * 16 + 8 + h] = s2;
    } else {
        if (t > b) return;
        int lo = 0, hi = n;
        while (lo < hi) { int mid = (lo + hi) >> 1; if (batch[mid] < t) lo = mid + 1; else hi = mid; }
        segst[t] = lo;
    }
}

// ---------------------------------------------------------------- [a_s|a_d] = h0 @ vsd
__global__ __launch_bounds__(256) void k_asd(const float* __restrict__ h0,
                                             const float* __restrict__ vsd,
                                             float* __restrict__ a_s, float* __restrict__ a_d) {
    __shared__ float hs[16][65];
    __shared__ float vl[64 * 16];
    int tid = threadIdx.x;
    int rbase = blockIdx.x * 16;
    {
        int row = tid / 16, c4 = (tid % 16) * 4;
        float4 hv = *(const float4*)(h0 + (size_t)(rbase + row) * 64 + c4);
        hs[row][c4] = hv.x; hs[row][c4 + 1] = hv.y; hs[row][c4 + 2] = hv.z; hs[row][c4 + 3] = hv.w;
    }
    #pragma unroll
    for (int j = 0; j < 4; j++) vl[tid + j * 256] = vsd[tid + j * 256];
    __syncthreads();
    int nl = tid / 16, o = tid % 16;
    float acc = 0.f;
    #pragma unroll 16
    for (int k = 0; k < 64; k++) acc += hs[nl][k] * vl[k * 16 + o];
    int node = rbase + nl;
    if (o < 8) a_s[node * 8 + o] = acc;
    else       a_d[node * 8 + (o - 8)] = acc;
}

// ---------------------------------------------------------------- CSR build
__global__ void k_count(const int* __restrict__ dst, int* __restrict__ deg, int e) {
    int i = blockIdx.x * 256 + threadIdx.x;
    if (i < e) atomicAdd(&deg[dst[i]], 1);
}

__global__ __launch_bounds__(1024) void k_scan1(const int* __restrict__ deg,
                                                int* __restrict__ tmp, int* __restrict__ bsum, int n) {
    __shared__ int wsum[16];
    int tid = threadIdx.x, lane = tid & 63, w = tid >> 6;
    int i = blockIdx.x * 1024 + tid;
    int v = (i < n) ? deg[i] + 1 : 0;   // +1 self loop
    int x = v;
    #pragma unroll
    for (int off = 1; off < 64; off <<= 1) {
        int t = __shfl_up(x, off);
        if (lane >= off) x += t;
    }
    if (lane == 63) wsum[w] = x;
    __syncthreads();
    int pre = 0;
    #pragma unroll
    for (int j = 0; j < 16; j++) if (j < w) pre += wsum[j];
    if (i < n) tmp[i] = pre + x - v;
    if (tid == 1023) bsum[blockIdx.x] = pre + x;
}

__global__ void k_scan2(const int* __restrict__ tmp, const int* __restrict__ bsum,
                        const float* __restrict__ a_s, const float* __restrict__ a_d,
                        int* __restrict__ offs, int* __restrict__ adj,
                        int* __restrict__ cursor, float* __restrict__ eb, int n, int nblk) {
    int i = blockIdx.x * 256 + threadIdx.x;
    if (i > n) return;
    int b = i >> 10;
    int pre = 0;
    for (int j = 0; j < b; j++) pre += bsum[j];
    if (i == n) {
        int tot = pre;
        for (int j = b; j < nblk; j++) tot += bsum[j];
        offs[n] = tot;
        return;
    }
    int o = pre + tmp[i];
    offs[i] = o;
    adj[o] = i;          // self loop first
    cursor[i] = o + 1;
    float4 s0 = *(const float4*)(a_s + (size_t)i * 8);
    float4 s1 = *(const float4*)(a_s + (size_t)i * 8 + 4);
    float4 d0 = *(const float4*)(a_d + (size_t)i * 8);
    float4 d1 = *(const float4*)(a_d + (size_t)i * 8 + 4);
    float4 e0, e1;
    e0.x = lrelu(s0.x + d0.x); e0.y = lrelu(s0.y + d0.y);
    e0.z = lrelu(s0.z + d0.z); e0.w = lrelu(s0.w + d0.w);
    e1.x = lrelu(s1.x + d1.x); e1.y = lrelu(s1.y + d1.y);
    e1.z = lrelu(s1.z + d1.z); e1.w = lrelu(s1.w + d1.w);
    *(float4*)(eb + (size_t)o * 8) = e0;
    *(float4*)(eb + (size_t)o * 8 + 4) = e1;
}

__global__ void k_fill_edge(const int* __restrict__ src, const int* __restrict__ dst,
                            const float* __restrict__ a_s, const float* __restrict__ a_d,
                            int* __restrict__ cursor, int* __restrict__ adj,
                            float* __restrict__ eb, int e) {
    int i = blockIdx.x * 256 + threadIdx.x;
    if (i >= e) return;
    int s = src[i], d = dst[i];
    int p = atomicAdd(&cursor[d], 1);
    adj[p] = s;
    float4 s0 = *(const float4*)(a_s + (size_t)s * 8);
    float4 s1 = *(const float4*)(a_s + (size_t)s * 8 + 4);
    float4 d0 = *(const float4*)(a_d + (size_t)d * 8);
    float4 d1 = *(const float4*)(a_d + (size_t)d * 8 + 4);
    float4 e0, e1;
    e0.x = lrelu(s0.x + d0.x); e0.y = lrelu(s0.y + d0.y);
    e0.z = lrelu(s0.z + d0.z); e0.w = lrelu(s0.w + d0.w);
    e1.x = lrelu(s1.x + d1.x); e1.y = lrelu(s1.y + d1.y);
    e1.z = lrelu(s1.z + d1.z); e1.w = lrelu(s1.w + d1.w);
    *(float4*)(eb + (size_t)p * 8) = e0;
    *(float4*)(eb + (size_t)p * 8 + 4) = e1;
}

// ---------------------------------------------------------------- GAT: softmax + aggregate h0 (1 wave/node)
__global__ __launch_bounds__(256) void k_gat3(const int* __restrict__ offs, const int* __restrict__ adj,
                                              const float* __restrict__ eb,
                                              const float* __restrict__ h0,
                                              float* __restrict__ agg_pre, int n) {
    int lane = threadIdx.x & 63;
    int node = blockIdx.x * 4 + (threadIdx.x >> 6);
    if (node >= n) return;
    int beg = offs[node], end = offs[node + 1];
    int g = lane >> 3;

    float m = -1e30f, s = 0.f;
    for (int base = beg; base < end; base += 8) {
        if (base + g < end) {
            float ev = eb[(size_t)base * 8 + lane];
            if (ev > m) { s = s * __expf(m - ev) + 1.f; m = ev; }
            else        { s += __expf(ev - m); }
        }
    }
    #pragma unroll
    for (int off = 8; off < 64; off <<= 1) {
        float mo = __shfl_xor(m, off), so = __shfl_xor(s, off);
        float mn = fmaxf(m, mo);
        s = s * __expf(m - mn) + so * __expf(mo - mn);
        m = mn;
    }
    float rcp = 1.f / s;

    float acc[8] = {0.f, 0.f, 0.f, 0.f, 0.f, 0.f, 0.f, 0.f};
    for (int sbase = beg; sbase < end; sbase += 64) {
        int scnt = end - sbase; if (scnt > 64) scnt = 64;
        int srcv = 0;
        if (lane < scnt) srcv = adj[sbase + lane];
        float al[8];
        #pragma unroll
        for (int j = 0; j < 8; j++) {
            int q = j * 8 + g;
            float ev = -1e30f;
            if (q < scnt) ev = eb[(size_t)sbase * 8 + j * 64 + lane];
            al[j] = __expf(ev - m) * rcp;
        }
        for (int j = 0; j < 8; j++) {
            int qb = j * 8;
            if (qb >= scnt) break;
            int sg[8]; float xv[8];
            #pragma unroll
            for (int g2 = 0; g2 < 8; g2++) sg[g2] = __shfl(srcv, qb + g2);
            #pragma unroll
            for (int g2 = 0; g2 < 8; g2++)
                xv[g2] = h0[(size_t)sg[g2] * 64 + lane];
            #pragma unroll
            for (int g2 = 0; g2 < 8; g2++) {
                #pragma unroll
                for (int h2 = 0; h2 < 8; h2++)
                    acc[h2] += __shfl(al[j], g2 * 8 + h2) * xv[g2];
            }
        }
    }
    #pragma unroll
    for (int h2 = 0; h2 < 8; h2++)
        agg_pre[(size_t)node * 512 + h2 * 64 + lane] = acc[h2];
}

// ---------------------------------------------------------------- fused head-pair double GEMM -> partials
// 64-row tile, 4x4 micro-tile; r-major LDS (stride 68), b128 broadcast A-reads
__global__ __launch_bounds__(256) void k_fused3(const float* __restrict__ agg_pre,
                                                const float* __restrict__ Wg,
                                                const float* __restrict__ bg,
                                                const float* __restrict__ Wh,
                                                float* __restrict__ part, int M) {
    __shared__ float As[64 * 68];
    __shared__ float Bs[64 * 64];
    __shared__ float Cs[64 * 68];
    int tid = threadIdx.x;
    int r0 = blockIdx.x * 64;
    int tx = tid % 16, ty = tid / 16;
    int rr = tid / 16, c4 = (tid % 16) * 4;
    float accO[4][4] = {};
    #pragma unroll
    for (int hh = 0; hh < 2; hh++) {
        int h = blockIdx.y * 2 + hh;
        // stage A (64x64, r-major) and Wg_h (k-major)
        #pragma unroll
        for (int pp = 0; pp < 4; pp++) {
            int r = rr + pp * 16;
            float4 av = make_float4(0.f, 0.f, 0.f, 0.f);
            if (r0 + r < M) av = *(const float4*)(agg_pre + (size_t)(r0 + r) * 512 + h * 64 + c4);
            *(float4*)&As[r * 68 + c4] = av;
            *(float4*)&Bs[r * 64 + c4] = *(const float4*)(Wg + (size_t)r * 512 + h * 64 + c4);
        }
        __syncthreads();
        float acc1[4][4] = {};
        #pragma unroll 4
        for (int kc = 0; kc < 16; kc++) {
            float4 b0 = *(const float4*)&Bs[(kc * 4 + 0) * 64 + tx * 4];
            float4 b1 = *(const float4*)&Bs[(kc * 4 + 1) * 64 + tx * 4];
            float4 b2 = *(const float4*)&Bs[(kc * 4 + 2) * 64 + tx * 4];
            float4 b3 = *(const float4*)&Bs[(kc * 4 + 3) * 64 + tx * 4];
            #pragma unroll
            for (int i = 0; i < 4; i++) {
                float4 a = *(const float4*)&As[(ty * 4 + i) * 68 + kc * 4];
                acc1[i][0] += a.x * b0.x + a.y * b1.x + a.z * b2.x + a.w * b3.x;
                acc1[i][1] += a.x * b0.y + a.y * b1.y + a.z * b2.y + a.w * b3.y;
                acc1[i][2] += a.x * b0.z + a.y * b1.z + a.z * b2.z + a.w * b3.z;
                acc1[i][3] += a.x * b0.w + a.y * b1.w + a.z * b2.w + a.w * b3.w;
            }
        }
        __syncthreads();   // done reading As/Bs
        float4 bgv = *(const float4*)(bg + h * 64 + tx * 4);
        #pragma unroll
        for (int i = 0; i < 4; i++) {
            float4 o;
            o.x = fmaxf(acc1[i][0] + bgv.x, 0.f);
            o.y = fmaxf(acc1[i][1] + bgv.y, 0.f);
            o.z = fmaxf(acc1[i][2] + bgv.z, 0.f);
            o.w = fmaxf(acc1[i][3] + bgv.w, 0.f);
            *(float4*)&Cs[(ty * 4 + i) * 68 + tx * 4] = o;
        }
        // stage Wh_h (k-major)
        #pragma unroll
        for (int pp = 0; pp < 4; pp++) {
            int k = rr + pp * 16;
            *(float4*)&Bs[k * 64 + c4] = *(const float4*)(Wh + (size_t)(h * 64 + k) * 64 + c4);
        }
        __syncthreads();
        #pragma unroll 4
        for (int kc = 0; kc < 16; kc++) {
            float4 b0 = *(const float4*)&Bs[(kc * 4 + 0) * 64 + tx * 4];
            float4 b1 = *(const float4*)&Bs[(kc * 4 + 1) * 64 + tx * 4];
            float4 b2 = *(const float4*)&Bs[(kc * 4 + 2) * 64 + tx * 4];
            float4 b3 = *(const float4*)&Bs[(kc * 4 + 3) * 64 + tx * 4];
            #pragma unroll
            for (int i = 0; i < 4; i++) {
                float4 a = *(const float4*)&Cs[(ty * 4 + i) * 68 + kc * 4];
                accO[i][0] += a.x * b0.x + a.y * b1.x + a.z * b2.x + a.w * b3.x;
                accO[i][1] += a.x * b0.y + a.y * b1.y + a.z * b2.y + a.w * b3.y;
                accO[i][2] += a.x * b0.z + a.y * b1.z + a.z * b2.z + a.w * b3.z;
                accO[i][3] += a.x * b0.w + a.y * b1.w + a.z * b2.w + a.w * b3.w;
            }
        }
        __syncthreads();   // before next head overwrites As/Bs/Cs
    }
    float* Cb = part + (size_t)blockIdx.y * M * 64;
    #pragma unroll
    for (int i = 0; i < 4; i++) {
        int r = r0 + ty * 4 + i;
        if (r >= M) continue;
        float4 o;
        o.x = accO[i][0]; o.y = accO[i][1]; o.z = accO[i][2]; o.w = accO[i][3];
        *(float4*)(Cb + (size_t)r * 64 + tx * 4) = o;
    }
}

// reduce 4 partials + bias + relu
__global__ void k_reduce4(const float* __restrict__ part, const float* __restrict__ bias,
                          float* __restrict__ out, int M) {
    int idx = blockIdx.x * 256 + threadIdx.x;
    if (idx >= M * 16) return;
    int r = idx / 16, cq = idx % 16;
    float4 s = make_float4(0.f, 0.f, 0.f, 0.f);
    #pragma unroll
    for (int y = 0; y < 4; y++) {
        float4 p = *(const float4*)(part + ((size_t)y * M + r) * 64 + cq * 4);
        s.x += p.x; s.y += p.y; s.z += p.z; s.w += p.w;
    }
    float4 b = *(const float4*)(bias + cq * 4);
    s.x = fmaxf(s.x + b.x, 0.f); s.y = fmaxf(s.y + b.y, 0.f);
    s.z = fmaxf(s.z + b.z, 0.f); s.w = fmaxf(s.w + b.w, 0.f);
    *(float4*)(out + (size_t)r * 64 + cq * 4) = s;
}

// ---------------------------------------------------------------- whole Set2Set (3 iters) + final MLP, 1 block / batch elem
#define SROWS 208
__global__ __launch_bounds__(256) void k_s2s(const float* __restrict__ out2,
                                             const int* __restrict__ segst,
                                             const float* __restrict__ W_ih, const float* __restrict__ W_hh,
                                             const float* __restrict__ b_ih, const float* __restrict__ b_hh,
                                             const float* __restrict__ W1, const float* __restrict__ b1,
                                             const float* __restrict__ W2, const float* __restrict__ b2,
                                             float* __restrict__ out) {
    int b = blockIdx.x, tid = threadIdx.x, lane = tid & 63, w = tid >> 6;
    __shared__ float sc[SROWS * 65];
    __shared__ float wlds[1024];
    __shared__ float hl[64], cl[64], rl[64];
    __shared__ float red[4];
    __shared__ float gsh[256];
    int beg = segst[b], end = segst[b + 1];
    int nrows = end - beg;
    int ncache = nrows < SROWS ? nrows : SROWS;
    for (int idx = tid; idx < ncache * 16; idx += 256) {
        int r = idx >> 4, q = idx & 15;
        float4 v = *(const float4*)(out2 + (size_t)(beg + r) * 64 + q * 4);
        float* p = &sc[r * 65 + q * 4];
        p[0] = v.x; p[1] = v.y; p[2] = v.z; p[3] = v.w;
    }
    if (tid < 64) { hl[tid] = 0.f; cl[tid] = 0.f; rl[tid] = 0.f; }
    __syncthreads();

    for (int it = 0; it < 3; it++) {
        {
            float acc = b_ih[tid] + b_hh[tid];
            const float* wi = W_ih + (size_t)tid * 128;
            const float* wh = W_hh + (size_t)tid * 64;
            #pragma unroll 8
            for (int k = 0; k < 64; k++) acc += hl[k] * (wi[k] + wh[k]) + rl[k] * wi[64 + k];
            gsh[tid] = acc;
        }
        __syncthreads();
        if (tid < 64) {
            float ig = gsh[tid], fg = gsh[64 + tid], gg = gsh[128 + tid], og = gsh[192 + tid];
            float cc = cl[tid];
            float si = 1.f / (1.f + __expf(-ig));
            float sf = 1.f / (1.f + __expf(-fg));
            float so = 1.f / (1.f + __expf(-og));
            float cn = sf * cc + si * tanhf(gg);
            cl[tid] = cn;
            hl[tid] = so * tanhf(cn);
        }
        __syncthreads();
        float ev[4];
        int nr = 0;
        float mloc = -1e30f;
        for (int i = tid; i < nrows; i += 256) {
            float d = 0.f;
            if (i < SROWS) {
                const float* rp = &sc[i * 65];
                #pragma unroll 16
                for (int j = 0; j < 64; j++) d += rp[j] * hl[j];
            } else {
                const float* rp = out2 + (size_t)(beg + i) * 64;
                for (int j = 0; j < 64; j++) d += rp[j] * hl[j];
            }
            ev[nr++] = d;
            mloc = fmaxf(mloc, d);
        }
        #pragma unroll
        for (int off = 1; off < 64; off <<= 1) mloc = fmaxf(mloc, __shfl_xor(mloc, off));
        if (lane == 0) red[w] = mloc;
        __syncthreads();
        float m = fmaxf(fmaxf(red[0], red[1]), fmaxf(red[2], red[3]));
        __syncthreads();
        float sloc = 0.f;
        nr = 0;
        for (int i = tid; i < nrows; i += 256) {
            float wv = __expf(ev[nr++] - m);
            if (i < 1024) wlds[i] = wv;
            sloc += wv;
        }
        #pragma unroll
        for (int off = 1; off < 64; off <<= 1) sloc += __shfl_xor(sloc, off);
        if (lane == 0) red[w] = sloc;
        __syncthreads();
        float sv = red[0] + red[1] + red[2] + red[3];
        float inv = sv > 0.f ? 1.f / sv : 0.f;
        float acc = 0.f;
        for (int i = w; i < nrows; i += 4) {
            float v = (i < SROWS) ? sc[i * 65 + lane] : out2[(size_t)(beg + i) * 64 + lane];
            acc += wlds[i] * v;
        }
        gsh[w * 64 + lane] = acc;
        __syncthreads();
        if (tid < 64)
            rl[tid] = (gsh[tid] + gsh[64 + tid] + gsh[128 + tid] + gsh[192 + tid]) * inv;
        __syncthreads();
    }
    if (tid < 64) {
        float t = b1[tid];
        #pragma unroll 8
        for (int k = 0; k < 64; k++)
            t += hl[k] * W1[(size_t)k * 64 + tid] + rl[k] * W1[(size_t)(64 + k) * 64 + tid];
        t = fmaxf(t, 0.f) * W2[tid];
        #pragma unroll
        for (int off = 32; off > 0; off >>= 1) t += __shfl_xor(t, off);
        if (tid == 0) out[b] = t + b2[0];
    }
}

// ----------------------------------------------------------------
extern "C" void kernel_launch(void* const* d_in, const int* in_sizes, int n_in,
                              void* d_out, int out_size, void* d_ws, size_t ws_size,
                              hipStream_t stream) {
    const float* x     = (const float*)d_in[0];
    const int*   ei    = (const int*)d_in[1];
    const int*   batch = (const int*)d_in[2];
    const float* W0    = (const float*)d_in[3];
    const float* b0    = (const float*)d_in[4];
    const float* Wg    = (const float*)d_in[5];
    const float* att_s = (const float*)d_in[6];
    const float* att_d = (const float*)d_in[7];
    const float* bg    = (const float*)d_in[8];
    const float* Wh    = (const float*)d_in[9];
    const float* bh    = (const float*)d_in[10];
    const float* W_ih  = (const float*)d_in[11];
    const float* W_hh  = (const float*)d_in[12];
    const float* b_ih  = (const float*)d_in[13];
    const float* b_hh  = (const float*)d_in[14];
    const float* W1    = (const float*)d_in[15];
    const float* b1    = (const float*)d_in[16];
    const float* W2    = (const float*)d_in[17];
    const float* b2    = (const float*)d_in[18];
    float* out = (float*)d_out;

    const int* esrc = ei;
    const int* edst = ei + N_EDGES;

    char* wsb = (char*)d_ws;
    size_t off = 0;
    auto alloc = [&](size_t bytes) {
        void* p = wsb + off;
        off = (off + bytes + 255) & ~(size_t)255;
        return p;
    };
    float* h0      = (float*)alloc((size_t)N_NODES * 64 * 4);
    float* agg_pre = (float*)alloc((size_t)N_NODES * 512 * 4);
    float* part    = (float*)alloc((size_t)4 * N_NODES * 64 * 4);
    float* out2    = (float*)alloc((size_t)N_NODES * 64 * 4);
    float* a_s     = (float*)alloc((size_t)N_NODES * 8 * 4);
    float* a_d     = (float*)alloc((size_t)N_NODES * 8 * 4);
    float* vsd     = (float*)alloc(64 * 16 * 4);
    float* eb      = (float*)alloc((size_t)(N_EDGES + N_NODES) * 8 * 4);
    int*   deg     = (int*)alloc((size_t)N_NODES * 4);
    int*   tmp     = (int*)alloc((size_t)N_NODES * 4);
    int*   bsum    = (int*)alloc(32 * 4);
    int*   offs    = (int*)alloc((size_t)(N_NODES + 1) * 4);
    int*   cursor  = (int*)alloc((size_t)N_NODES * 4);
    int*   adj     = (int*)alloc((size_t)(N_EDGES + N_NODES) * 4);
    int*   segst   = (int*)alloc((size_t)(NBATCH + 1) * 4);

    // node MLP (+zero deg), tiny setup (vsd + bounds), attention dots
    k_h0<<<(N_NODES + 3) / 4, 256, 0, stream>>>(x, W0, b0, h0, deg, N_NODES);
    k_small<<<2, 512, 0, stream>>>(Wg, att_s, att_d, vsd, batch, segst, N_NODES, NBATCH);
    k_asd<<<N_NODES / 16, 256, 0, stream>>>(h0, vsd, a_s, a_d);

    // CSR by dst (with self loops) + per-position logits
    k_count<<<(N_EDGES + 255) / 256, 256, 0, stream>>>(edst, deg, N_EDGES);
    const int nblk = (N_NODES + 1023) / 1024;
    k_scan1<<<nblk, 1024, 0, stream>>>(deg, tmp, bsum, N_NODES);
    k_scan2<<<(N_NODES + 256) / 256, 256, 0, stream>>>(tmp, bsum, a_s, a_d, offs, adj, cursor, eb, N_NODES, nblk);
    k_fill_edge<<<(N_EDGES + 255) / 256, 256, 0, stream>>>(esrc, edst, a_s, a_d, cursor, adj, eb, N_EDGES);

    // GAT aggregate + fused 64-row head-pair double-GEMM (partials) + reduce
    k_gat3<<<(N_NODES + 3) / 4, 256, 0, stream>>>(offs, adj, eb, h0, agg_pre, N_NODES);
    k_fused3<<<dim3((N_NODES + 63) / 64, 4), 256, 0, stream>>>(agg_pre, Wg, bg, Wh, part, N_NODES);
    k_reduce4<<<(N_NODES * 16 + 255) / 256, 256, 0, stream>>>(part, bh, out2, N_NODES);

    // Set2Set (3 iters) + final MLP, one kernel
    k_s2s<<<NBATCH, 256, 0, stream>>>(out2, segst, W_ih, W_hh, b_ih, b_hh, W1, b1, W2, b2, out);
}

// Round 8
// 294.490 us; speedup vs baseline: 1.0542x; 1.0542x over previous
//
#include <hip/hip_runtime.h>

#define N_NODES 20000
#define N_EDGES 320000
#define NBATCH  128

__device__ __forceinline__ float lrelu(float v) { return v > 0.f ? v : 0.2f * v; }

// ---------------------------------------------------------------- h0 = relu(x@W0+b0); also zero deg
__global__ void k_h0(const float* __restrict__ x, const float* __restrict__ W0,
                     const float* __restrict__ b0, float* __restrict__ h0,
                     int* __restrict__ deg, int n) {
    __shared__ float ws[25 * 64];
    __shared__ float bs[64];
    __shared__ float xs[100];
    int t = threadIdx.x;
    int gid = blockIdx.x * 256 + t;
    if (gid < n) deg[gid] = 0;
    for (int i = t; i < 25 * 64; i += 256) ws[i] = W0[i];
    if (t < 64) bs[t] = b0[t];
    int nb = blockIdx.x * 4;
    if (t < 100 && nb * 25 + t < n * 25) xs[t] = x[(size_t)nb * 25 + t];
    __syncthreads();
    int node = nb + (t >> 6);
    int c = t & 63;
    if (node >= n) return;
    float s = bs[c];
    const float* xr = xs + (t >> 6) * 25;
    #pragma unroll
    for (int k = 0; k < 25; k++) s += xr[k] * ws[k * 64 + c];
    h0[(size_t)node * 64 + c] = fmaxf(s, 0.f);
}

// ---------------------------------------------------------------- merged tiny setup: vsd + segment bounds
__global__ void k_small(const float* __restrict__ Wg, const float* __restrict__ att_s,
                        const float* __restrict__ att_d, float* __restrict__ vsd,
                        const int* __restrict__ batch, int* __restrict__ segst, int n, int b) {
    int t = threadIdx.x;
    if (blockIdx.x == 0) {
        int k = t >> 3, h = t & 7;
        const float* wrow = Wg + (size_t)k * 512 + h * 64;
        float s1 = 0.f, s2 = 0.f;
        #pragma unroll 8
        for (int c = 0; c < 64; c++) {
            float w = wrow[c];
            s1 += w * att_s[h * 64 + c];
            s2 += w * att_d[h * 64 + c];
        }
        vsd[k * 16 + h] = s1;
        vsd[k * 16 + 8 + h] = s2;
    } else {
        if (t > b) return;
        int lo = 0, hi = n;
        while (lo < hi) { int mid = (lo + hi) >> 1; if (batch[mid] < t) lo = mid + 1; else hi = mid; }
        segst[t] = lo;
    }
}

// ---------------------------------------------------------------- [a_s|a_d] = h0 @ vsd
__global__ __launch_bounds__(256) void k_asd(const float* __restrict__ h0,
                                             const float* __restrict__ vsd,
                                             float* __restrict__ a_s, float* __restrict__ a_d) {
    __shared__ float hs[16][65];
    __shared__ float vl[64 * 16];
    int tid = threadIdx.x;
    int rbase = blockIdx.x * 16;
    {
        int row = tid / 16, c4 = (tid % 16) * 4;
        float4 hv = *(const float4*)(h0 + (size_t)(rbase + row) * 64 + c4);
        hs[row][c4] = hv.x; hs[row][c4 + 1] = hv.y; hs[row][c4 + 2] = hv.z; hs[row][c4 + 3] = hv.w;
    }
    #pragma unroll
    for (int j = 0; j < 4; j++) vl[tid + j * 256] = vsd[tid + j * 256];
    __syncthreads();
    int nl = tid / 16, o = tid % 16;
    float acc = 0.f;
    #pragma unroll 16
    for (int k = 0; k < 64; k++) acc += hs[nl][k] * vl[k * 16 + o];
    int node = rbase + nl;
    if (o < 8) a_s[node * 8 + o] = acc;
    else       a_d[node * 8 + (o - 8)] = acc;
}

// ---------------------------------------------------------------- CSR build
__global__ void k_count(const int* __restrict__ dst, int* __restrict__ deg, int e) {
    int i = blockIdx.x * 256 + threadIdx.x;
    if (i < e) atomicAdd(&deg[dst[i]], 1);
}

__global__ __launch_bounds__(1024) void k_scan1(const int* __restrict__ deg,
                                                int* __restrict__ tmp, int* __restrict__ bsum, int n) {
    __shared__ int wsum[16];
    int tid = threadIdx.x, lane = tid & 63, w = tid >> 6;
    int i = blockIdx.x * 1024 + tid;
    int v = (i < n) ? deg[i] + 1 : 0;   // +1 self loop
    int x = v;
    #pragma unroll
    for (int off = 1; off < 64; off <<= 1) {
        int t = __shfl_up(x, off);
        if (lane >= off) x += t;
    }
    if (lane == 63) wsum[w] = x;
    __syncthreads();
    int pre = 0;
    #pragma unroll
    for (int j = 0; j < 16; j++) if (j < w) pre += wsum[j];
    if (i < n) tmp[i] = pre + x - v;
    if (tid == 1023) bsum[blockIdx.x] = pre + x;
}

__global__ void k_scan2(const int* __restrict__ tmp, const int* __restrict__ bsum,
                        const float* __restrict__ a_s, const float* __restrict__ a_d,
                        int* __restrict__ offs, int* __restrict__ adj,
                        int* __restrict__ cursor, float* __restrict__ eb, int n, int nblk) {
    int i = blockIdx.x * 256 + threadIdx.x;
    if (i > n) return;
    int b = i >> 10;
    int pre = 0;
    for (int j = 0; j < b; j++) pre += bsum[j];
    if (i == n) {
        int tot = pre;
        for (int j = b; j < nblk; j++) tot += bsum[j];
        offs[n] = tot;
        return;
    }
    int o = pre + tmp[i];
    offs[i] = o;
    adj[o] = i;          // self loop first
    cursor[i] = o + 1;
    float4 s0 = *(const float4*)(a_s + (size_t)i * 8);
    float4 s1 = *(const float4*)(a_s + (size_t)i * 8 + 4);
    float4 d0 = *(const float4*)(a_d + (size_t)i * 8);
    float4 d1 = *(const float4*)(a_d + (size_t)i * 8 + 4);
    float4 e0, e1;
    e0.x = lrelu(s0.x + d0.x); e0.y = lrelu(s0.y + d0.y);
    e0.z = lrelu(s0.z + d0.z); e0.w = lrelu(s0.w + d0.w);
    e1.x = lrelu(s1.x + d1.x); e1.y = lrelu(s1.y + d1.y);
    e1.z = lrelu(s1.z + d1.z); e1.w = lrelu(s1.w + d1.w);
    *(float4*)(eb + (size_t)o * 8) = e0;
    *(float4*)(eb + (size_t)o * 8 + 4) = e1;
}

__global__ void k_fill_edge(const int* __restrict__ src, const int* __restrict__ dst,
                            const float* __restrict__ a_s, const float* __restrict__ a_d,
                            int* __restrict__ cursor, int* __restrict__ adj,
                            float* __restrict__ eb, int e) {
    int i = blockIdx.x * 256 + threadIdx.x;
    if (i >= e) return;
    int s = src[i], d = dst[i];
    int p = atomicAdd(&cursor[d], 1);
    adj[p] = s;
    float4 s0 = *(const float4*)(a_s + (size_t)s * 8);
    float4 s1 = *(const float4*)(a_s + (size_t)s * 8 + 4);
    float4 d0 = *(const float4*)(a_d + (size_t)d * 8);
    float4 d1 = *(const float4*)(a_d + (size_t)d * 8 + 4);
    float4 e0, e1;
    e0.x = lrelu(s0.x + d0.x); e0.y = lrelu(s0.y + d0.y);
    e0.z = lrelu(s0.z + d0.z); e0.w = lrelu(s0.w + d0.w);
    e1.x = lrelu(s1.x + d1.x); e1.y = lrelu(s1.y + d1.y);
    e1.z = lrelu(s1.z + d1.z); e1.w = lrelu(s1.w + d1.w);
    *(float4*)(eb + (size_t)p * 8) = e0;
    *(float4*)(eb + (size_t)p * 8 + 4) = e1;
}

// ---------------------------------------------------------------- GAT: softmax + aggregate h0 (1 wave/node)
__global__ __launch_bounds__(256) void k_gat3(const int* __restrict__ offs, const int* __restrict__ adj,
                                              const float* __restrict__ eb,
                                              const float* __restrict__ h0,
                                              float* __restrict__ agg_pre, int n) {
    int lane = threadIdx.x & 63;
    int node = blockIdx.x * 4 + (threadIdx.x >> 6);
    if (node >= n) return;
    int beg = offs[node], end = offs[node + 1];
    int g = lane >> 3;

    float m = -1e30f, s = 0.f;
    for (int base = beg; base < end; base += 8) {
        if (base + g < end) {
            float ev = eb[(size_t)base * 8 + lane];
            if (ev > m) { s = s * __expf(m - ev) + 1.f; m = ev; }
            else        { s += __expf(ev - m); }
        }
    }
    #pragma unroll
    for (int off = 8; off < 64; off <<= 1) {
        float mo = __shfl_xor(m, off), so = __shfl_xor(s, off);
        float mn = fmaxf(m, mo);
        s = s * __expf(m - mn) + so * __expf(mo - mn);
        m = mn;
    }
    float rcp = 1.f / s;

    float acc[8] = {0.f, 0.f, 0.f, 0.f, 0.f, 0.f, 0.f, 0.f};
    for (int sbase = beg; sbase < end; sbase += 64) {
        int scnt = end - sbase; if (scnt > 64) scnt = 64;
        int srcv = 0;
        if (lane < scnt) srcv = adj[sbase + lane];
        float al[8];
        #pragma unroll
        for (int j = 0; j < 8; j++) {
            int q = j * 8 + g;
            float ev = -1e30f;
            if (q < scnt) ev = eb[(size_t)sbase * 8 + j * 64 + lane];
            al[j] = __expf(ev - m) * rcp;
        }
        for (int j = 0; j < 8; j++) {
            int qb = j * 8;
            if (qb >= scnt) break;
            int sg[8]; float xv[8];
            #pragma unroll
            for (int g2 = 0; g2 < 8; g2++) sg[g2] = __shfl(srcv, qb + g2);
            #pragma unroll
            for (int g2 = 0; g2 < 8; g2++)
                xv[g2] = h0[(size_t)sg[g2] * 64 + lane];
            #pragma unroll
            for (int g2 = 0; g2 < 8; g2++) {
                #pragma unroll
                for (int h2 = 0; h2 < 8; h2++)
                    acc[h2] += __shfl(al[j], g2 * 8 + h2) * xv[g2];
            }
        }
    }
    #pragma unroll
    for (int h2 = 0; h2 < 8; h2++)
        agg_pre[(size_t)node * 512 + h2 * 64 + lane] = acc[h2];
}

// ---------------------------------------------------------------- fused head-pair double GEMM -> partials
// 64-row tile, thread = 2 rows x 8 cols; As/Cs share one LDS buffer (33.8 KB total)
__global__ __launch_bounds__(256) void k_fused4(const float* __restrict__ agg_pre,
                                                const float* __restrict__ Wg,
                                                const float* __restrict__ bg,
                                                const float* __restrict__ Wh,
                                                float* __restrict__ part, int M) {
    __shared__ float AB[64 * 68];   // A for GEMM1, then C for GEMM2 (r-major, stride 68)
    __shared__ float Bs[64 * 64];   // Wg_h, then Wh_h (k-major)
    int tid = threadIdx.x;
    int r0 = blockIdx.x * 64;
    int tx = tid & 7;          // col group: cols tx*8 .. tx*8+7
    int ty = tid >> 3;         // row group: rows ty*2, ty*2+1
    int rr = tid >> 4, c4 = (tid & 15) * 4;   // staging map
    float4 accO[2][2] = {};
    #pragma unroll
    for (int hh = 0; hh < 2; hh++) {
        int h = blockIdx.y * 2 + hh;
        // stage A (64x64 r-major) and Wg_h (64x64 k-major)
        #pragma unroll
        for (int pp = 0; pp < 4; pp++) {
            int r = rr + pp * 16;
            float4 av = make_float4(0.f, 0.f, 0.f, 0.f);
            if (r0 + r < M) av = *(const float4*)(agg_pre + (size_t)(r0 + r) * 512 + h * 64 + c4);
            *(float4*)&AB[r * 68 + c4] = av;
            *(float4*)&Bs[r * 64 + c4] = *(const float4*)(Wg + (size_t)r * 512 + h * 64 + c4);
        }
        __syncthreads();
        // GEMM1: acc1 = A @ Wg_h
        float4 acc1[2][2] = {};
        #pragma unroll 4
        for (int kc = 0; kc < 16; kc++) {
            float4 a0 = *(const float4*)&AB[(ty * 2 + 0) * 68 + kc * 4];
            float4 a1 = *(const float4*)&AB[(ty * 2 + 1) * 68 + kc * 4];
            #pragma unroll
            for (int kk = 0; kk < 4; kk++) {
                float ak0 = (&a0.x)[kk], ak1 = (&a1.x)[kk];
                float4 bL = *(const float4*)&Bs[(kc * 4 + kk) * 64 + tx * 8];
                float4 bH = *(const float4*)&Bs[(kc * 4 + kk) * 64 + tx * 8 + 4];
                acc1[0][0].x += ak0 * bL.x; acc1[0][0].y += ak0 * bL.y; acc1[0][0].z += ak0 * bL.z; acc1[0][0].w += ak0 * bL.w;
                acc1[0][1].x += ak0 * bH.x; acc1[0][1].y += ak0 * bH.y; acc1[0][1].z += ak0 * bH.z; acc1[0][1].w += ak0 * bH.w;
                acc1[1][0].x += ak1 * bL.x; acc1[1][0].y += ak1 * bL.y; acc1[1][0].z += ak1 * bL.z; acc1[1][0].w += ak1 * bL.w;
                acc1[1][1].x += ak1 * bH.x; acc1[1][1].y += ak1 * bH.y; acc1[1][1].z += ak1 * bH.z; acc1[1][1].w += ak1 * bH.w;
            }
        }
        __syncthreads();   // done reading AB/Bs
        // C = relu(acc1 + bg) -> AB buffer; stage Wh_h -> Bs
        float4 bgL = *(const float4*)(bg + h * 64 + tx * 8);
        float4 bgH = *(const float4*)(bg + h * 64 + tx * 8 + 4);
        #pragma unroll
        for (int i = 0; i < 2; i++) {
            float4 cL, cH;
            cL.x = fmaxf(acc1[i][0].x + bgL.x, 0.f); cL.y = fmaxf(acc1[i][0].y + bgL.y, 0.f);
            cL.z = fmaxf(acc1[i][0].z + bgL.z, 0.f); cL.w = fmaxf(acc1[i][0].w + bgL.w, 0.f);
            cH.x = fmaxf(acc1[i][1].x + bgH.x, 0.f); cH.y = fmaxf(acc1[i][1].y + bgH.y, 0.f);
            cH.z = fmaxf(acc1[i][1].z + bgH.z, 0.f); cH.w = fmaxf(acc1[i][1].w + bgH.w, 0.f);
            *(float4*)&AB[(ty * 2 + i) * 68 + tx * 8] = cL;
            *(float4*)&AB[(ty * 2 + i) * 68 + tx * 8 + 4] = cH;
        }
        #pragma unroll
        for (int pp = 0; pp < 4; pp++) {
            int k = rr + pp * 16;
            *(float4*)&Bs[k * 64 + c4] = *(const float4*)(Wh + (size_t)(h * 64 + k) * 64 + c4);
        }
        __syncthreads();
        // GEMM2: accO += C @ Wh_h
        #pragma unroll 4
        for (int kc = 0; kc < 16; kc++) {
            float4 a0 = *(const float4*)&AB[(ty * 2 + 0) * 68 + kc * 4];
            float4 a1 = *(const float4*)&AB[(ty * 2 + 1) * 68 + kc * 4];
            #pragma unroll
            for (int kk = 0; kk < 4; kk++) {
                float ak0 = (&a0.x)[kk], ak1 = (&a1.x)[kk];
                float4 bL = *(const float4*)&Bs[(kc * 4 + kk) * 64 + tx * 8];
                float4 bH = *(const float4*)&Bs[(kc * 4 + kk) * 64 + tx * 8 + 4];
                accO[0][0].x += ak0 * bL.x; accO[0][0].y += ak0 * bL.y; accO[0][0].z += ak0 * bL.z; accO[0][0].w += ak0 * bL.w;
                accO[0][1].x += ak0 * bH.x; accO[0][1].y += ak0 * bH.y; accO[0][1].z += ak0 * bH.z; accO[0][1].w += ak0 * bH.w;
                accO[1][0].x += ak1 * bL.x; accO[1][0].y += ak1 * bL.y; accO[1][0].z += ak1 * bL.z; accO[1][0].w += ak1 * bL.w;
                accO[1][1].x += ak1 * bH.x; accO[1][1].y += ak1 * bH.y; accO[1][1].z += ak1 * bH.z; accO[1][1].w += ak1 * bH.w;
            }
        }
        __syncthreads();   // before next head restages AB/Bs
    }
    float* Cb = part + (size_t)blockIdx.y * M * 64;
    #pragma unroll
    for (int i = 0; i < 2; i++) {
        int r = r0 + ty * 2 + i;
        if (r >= M) continue;
        *(float4*)(Cb + (size_t)r * 64 + tx * 8) = accO[i][0];
        *(float4*)(Cb + (size_t)r * 64 + tx * 8 + 4) = accO[i][1];
    }
}

// ---------------------------------------------------------------- Set2Set (3 iters) + final MLP; sums 4 partials + bh + relu on load
#define SROWS 208
__global__ __launch_bounds__(256) void k_s2s(const float* __restrict__ part,
                                             const float* __restrict__ bh,
                                             const int* __restrict__ segst,
                                             const float* __restrict__ W_ih, const float* __restrict__ W_hh,
                                             const float* __restrict__ b_ih, const float* __restrict__ b_hh,
                                             const float* __restrict__ W1, const float* __restrict__ b1,
                                             const float* __restrict__ W2, const float* __restrict__ b2,
                                             float* __restrict__ out, int M) {
    int b = blockIdx.x, tid = threadIdx.x, lane = tid & 63, w = tid >> 6;
    __shared__ float sc[SROWS * 65];
    __shared__ float wlds[1024];
    __shared__ float hl[64], cl[64], rl[64];
    __shared__ float red[4];
    __shared__ float gsh[256];
    int beg = segst[b], end = segst[b + 1];
    int nrows = end - beg;
    int ncache = nrows < SROWS ? nrows : SROWS;
    const size_t PS = (size_t)M * 64;
    for (int idx = tid; idx < ncache * 16; idx += 256) {
        int r = idx >> 4, q = idx & 15;
        const float* pb = part + (size_t)(beg + r) * 64 + q * 4;
        float4 v0 = *(const float4*)pb;
        float4 v1 = *(const float4*)(pb + PS);
        float4 v2 = *(const float4*)(pb + 2 * PS);
        float4 v3 = *(const float4*)(pb + 3 * PS);
        float4 bv = *(const float4*)(bh + q * 4);
        float* p = &sc[r * 65 + q * 4];
        p[0] = fmaxf(v0.x + v1.x + v2.x + v3.x + bv.x, 0.f);
        p[1] = fmaxf(v0.y + v1.y + v2.y + v3.y + bv.y, 0.f);
        p[2] = fmaxf(v0.z + v1.z + v2.z + v3.z + bv.z, 0.f);
        p[3] = fmaxf(v0.w + v1.w + v2.w + v3.w + bv.w, 0.f);
    }
    if (tid < 64) { hl[tid] = 0.f; cl[tid] = 0.f; rl[tid] = 0.f; }
    __syncthreads();

    for (int it = 0; it < 3; it++) {
        {
            float acc = b_ih[tid] + b_hh[tid];
            const float* wi = W_ih + (size_t)tid * 128;
            const float* wh = W_hh + (size_t)tid * 64;
            #pragma unroll 8
            for (int k = 0; k < 64; k++) acc += hl[k] * (wi[k] + wh[k]) + rl[k] * wi[64 + k];
            gsh[tid] = acc;
        }
        __syncthreads();
        if (tid < 64) {
            float ig = gsh[tid], fg = gsh[64 + tid], gg = gsh[128 + tid], og = gsh[192 + tid];
            float cc = cl[tid];
            float si = 1.f / (1.f + __expf(-ig));
            float sf = 1.f / (1.f + __expf(-fg));
            float so = 1.f / (1.f + __expf(-og));
            float cn = sf * cc + si * tanhf(gg);
            cl[tid] = cn;
            hl[tid] = so * tanhf(cn);
        }
        __syncthreads();
        float ev[4];
        int nr = 0;
        float mloc = -1e30f;
        for (int i = tid; i < nrows; i += 256) {
            float d = 0.f;
            if (i < SROWS) {
                const float* rp = &sc[i * 65];
                #pragma unroll 16
                for (int j = 0; j < 64; j++) d += rp[j] * hl[j];
            } else {
                const float* pb = part + (size_t)(beg + i) * 64;
                for (int j = 0; j < 64; j++) {
                    float v = pb[j] + pb[PS + j] + pb[2 * PS + j] + pb[3 * PS + j] + bh[j];
                    d += fmaxf(v, 0.f) * hl[j];
                }
            }
            ev[nr++] = d;
            mloc = fmaxf(mloc, d);
        }
        #pragma unroll
        for (int off = 1; off < 64; off <<= 1) mloc = fmaxf(mloc, __shfl_xor(mloc, off));
        if (lane == 0) red[w] = mloc;
        __syncthreads();
        float m = fmaxf(fmaxf(red[0], red[1]), fmaxf(red[2], red[3]));
        __syncthreads();
        float sloc = 0.f;
        nr = 0;
        for (int i = tid; i < nrows; i += 256) {
            float wv = __expf(ev[nr++] - m);
            if (i < 1024) wlds[i] = wv;
            sloc += wv;
        }
        #pragma unroll
        for (int off = 1; off < 64; off <<= 1) sloc += __shfl_xor(sloc, off);
        if (lane == 0) red[w] = sloc;
        __syncthreads();
        float sv = red[0] + red[1] + red[2] + red[3];
        float inv = sv > 0.f ? 1.f / sv : 0.f;
        float acc = 0.f;
        for (int i = w; i < nrows; i += 4) {
            float v;
            if (i < SROWS) v = sc[i * 65 + lane];
            else {
                const float* pb = part + (size_t)(beg + i) * 64 + lane;
                v = fmaxf(pb[0] + pb[PS] + pb[2 * PS] + pb[3 * PS] + bh[lane], 0.f);
            }
            acc += wlds[i] * v;
        }
        gsh[w * 64 + lane] = acc;
        __syncthreads();
        if (tid < 64)
            rl[tid] = (gsh[tid] + gsh[64 + tid] + gsh[128 + tid] + gsh[192 + tid]) * inv;
        __syncthreads();
    }
    if (tid < 64) {
        float t = b1[tid];
        #pragma unroll 8
        for (int k = 0; k < 64; k++)
            t += hl[k] * W1[(size_t)k * 64 + tid] + rl[k] * W1[(size_t)(64 + k) * 64 + tid];
        t = fmaxf(t, 0.f) * W2[tid];
        #pragma unroll
        for (int off = 32; off > 0; off >>= 1) t += __shfl_xor(t, off);
        if (tid == 0) out[b] = t + b2[0];
    }
}

// ----------------------------------------------------------------
extern "C" void kernel_launch(void* const* d_in, const int* in_sizes, int n_in,
                              void* d_out, int out_size, void* d_ws, size_t ws_size,
                              hipStream_t stream) {
    const float* x     = (const float*)d_in[0];
    const int*   ei    = (const int*)d_in[1];
    const int*   batch = (const int*)d_in[2];
    const float* W0    = (const float*)d_in[3];
    const float* b0    = (const float*)d_in[4];
    const float* Wg    = (const float*)d_in[5];
    const float* att_s = (const float*)d_in[6];
    const float* att_d = (const float*)d_in[7];
    const float* bg    = (const float*)d_in[8];
    const float* Wh    = (const float*)d_in[9];
    const float* bh    = (const float*)d_in[10];
    const float* W_ih  = (const float*)d_in[11];
    const float* W_hh  = (const float*)d_in[12];
    const float* b_ih  = (const float*)d_in[13];
    const float* b_hh  = (const float*)d_in[14];
    const float* W1    = (const float*)d_in[15];
    const float* b1    = (const float*)d_in[16];
    const float* W2    = (const float*)d_in[17];
    const float* b2    = (const float*)d_in[18];
    float* out = (float*)d_out;

    const int* esrc = ei;
    const int* edst = ei + N_EDGES;

    char* wsb = (char*)d_ws;
    size_t off = 0;
    auto alloc = [&](size_t bytes) {
        void* p = wsb + off;
        off = (off + bytes + 255) & ~(size_t)255;
        return p;
    };
    float* h0      = (float*)alloc((size_t)N_NODES * 64 * 4);
    float* agg_pre = (float*)alloc((size_t)N_NODES * 512 * 4);
    float* part    = (float*)alloc((size_t)4 * N_NODES * 64 * 4);
    float* a_s     = (float*)alloc((size_t)N_NODES * 8 * 4);
    float* a_d     = (float*)alloc((size_t)N_NODES * 8 * 4);
    float* vsd     = (float*)alloc(64 * 16 * 4);
    float* eb      = (float*)alloc((size_t)(N_EDGES + N_NODES) * 8 * 4);
    int*   deg     = (int*)alloc((size_t)N_NODES * 4);
    int*   tmp     = (int*)alloc((size_t)N_NODES * 4);
    int*   bsum    = (int*)alloc(32 * 4);
    int*   offs    = (int*)alloc((size_t)(N_NODES + 1) * 4);
    int*   cursor  = (int*)alloc((size_t)N_NODES * 4);
    int*   adj     = (int*)alloc((size_t)(N_EDGES + N_NODES) * 4);
    int*   segst   = (int*)alloc((size_t)(NBATCH + 1) * 4);

    // node MLP (+zero deg), tiny setup (vsd + bounds), attention dots
    k_h0<<<(N_NODES + 3) / 4, 256, 0, stream>>>(x, W0, b0, h0, deg, N_NODES);
    k_small<<<2, 512, 0, stream>>>(Wg, att_s, att_d, vsd, batch, segst, N_NODES, NBATCH);
    k_asd<<<N_NODES / 16, 256, 0, stream>>>(h0, vsd, a_s, a_d);

    // CSR by dst (with self loops) + per-position logits
    k_count<<<(N_EDGES + 255) / 256, 256, 0, stream>>>(edst, deg, N_EDGES);
    const int nblk = (N_NODES + 1023) / 1024;
    k_scan1<<<nblk, 1024, 0, stream>>>(deg, tmp, bsum, N_NODES);
    k_scan2<<<(N_NODES + 256) / 256, 256, 0, stream>>>(tmp, bsum, a_s, a_d, offs, adj, cursor, eb, N_NODES, nblk);
    k_fill_edge<<<(N_EDGES + 255) / 256, 256, 0, stream>>>(esrc, edst, a_s, a_d, cursor, adj, eb, N_EDGES);

    // GAT aggregate + fused 64-row head-pair double-GEMM (partials)
    k_gat3<<<(N_NODES + 3) / 4, 256, 0, stream>>>(offs, adj, eb, h0, agg_pre, N_NODES);
    k_fused4<<<dim3((N_NODES + 63) / 64, 4), 256, 0, stream>>>(agg_pre, Wg, bg, Wh, part, N_NODES);

    // Set2Set (3 iters) + final MLP, one kernel (sums partials on load)
    k_s2s<<<NBATCH, 256, 0, stream>>>(part, bh, segst, W_ih, W_hh, b_ih, b_hh, W1, b1, W2, b2, out, N_NODES);
}

// Round 9
// 269.239 us; speedup vs baseline: 1.1530x; 1.0938x over previous
//
#include <hip/hip_runtime.h>

#define N_NODES 20000
#define N_EDGES 320000
#define NBATCH  128

__device__ __forceinline__ float lrelu(float v) { return v > 0.f ? v : 0.2f * v; }
__device__ __forceinline__ float rdlane(float v, int l) {
    return __int_as_float(__builtin_amdgcn_readlane(__float_as_int(v), l));
}

// ---------------------------------------------------------------- h0 = relu(x@W0+b0); also zero deg
__global__ void k_h0(const float* __restrict__ x, const float* __restrict__ W0,
                     const float* __restrict__ b0, float* __restrict__ h0,
                     int* __restrict__ deg, int n) {
    __shared__ float ws[25 * 64];
    __shared__ float bs[64];
    __shared__ float xs[100];
    int t = threadIdx.x;
    int gid = blockIdx.x * 256 + t;
    if (gid < n) deg[gid] = 0;
    for (int i = t; i < 25 * 64; i += 256) ws[i] = W0[i];
    if (t < 64) bs[t] = b0[t];
    int nb = blockIdx.x * 4;
    if (t < 100 && nb * 25 + t < n * 25) xs[t] = x[(size_t)nb * 25 + t];
    __syncthreads();
    int node = nb + (t >> 6);
    int c = t & 63;
    if (node >= n) return;
    float s = bs[c];
    const float* xr = xs + (t >> 6) * 25;
    #pragma unroll
    for (int k = 0; k < 25; k++) s += xr[k] * ws[k * 64 + c];
    h0[(size_t)node * 64 + c] = fmaxf(s, 0.f);
}

// ---------------------------------------------------------------- merged tiny setup: vsd + segment bounds
__global__ void k_small(const float* __restrict__ Wg, const float* __restrict__ att_s,
                        const float* __restrict__ att_d, float* __restrict__ vsd,
                        const int* __restrict__ batch, int* __restrict__ segst, int n, int b) {
    int t = threadIdx.x;
    if (blockIdx.x == 0) {
        int k = t >> 3, h = t & 7;
        const float* wrow = Wg + (size_t)k * 512 + h * 64;
        float s1 = 0.f, s2 = 0.f;
        #pragma unroll 8
        for (int c = 0; c < 64; c++) {
            float w = wrow[c];
            s1 += w * att_s[h * 64 + c];
            s2 += w * att_d[h * 64 + c];
        }
        vsd[k * 16 + h] = s1;
        vsd[k * 16 + 8 + h] = s2;
    } else {
        if (t > b) return;
        int lo = 0, hi = n;
        while (lo < hi) { int mid = (lo + hi) >> 1; if (batch[mid] < t) lo = mid + 1; else hi = mid; }
        segst[t] = lo;
    }
}

// ---------------------------------------------------------------- [a_s|a_d] = h0 @ vsd
__global__ __launch_bounds__(256) void k_asd(const float* __restrict__ h0,
                                             const float* __restrict__ vsd,
                                             float* __restrict__ a_s, float* __restrict__ a_d) {
    __shared__ float hs[16][65];
    __shared__ float vl[64 * 16];
    int tid = threadIdx.x;
    int rbase = blockIdx.x * 16;
    {
        int row = tid / 16, c4 = (tid % 16) * 4;
        float4 hv = *(const float4*)(h0 + (size_t)(rbase + row) * 64 + c4);
        hs[row][c4] = hv.x; hs[row][c4 + 1] = hv.y; hs[row][c4 + 2] = hv.z; hs[row][c4 + 3] = hv.w;
    }
    #pragma unroll
    for (int j = 0; j < 4; j++) vl[tid + j * 256] = vsd[tid + j * 256];
    __syncthreads();
    int nl = tid / 16, o = tid % 16;
    float acc = 0.f;
    #pragma unroll 16
    for (int k = 0; k < 64; k++) acc += hs[nl][k] * vl[k * 16 + o];
    int node = rbase + nl;
    if (o < 8) a_s[node * 8 + o] = acc;
    else       a_d[node * 8 + (o - 8)] = acc;
}

// ---------------------------------------------------------------- CSR build
__global__ void k_count(const int* __restrict__ dst, int* __restrict__ deg, int e) {
    int i = blockIdx.x * 256 + threadIdx.x;
    if (i < e) atomicAdd(&deg[dst[i]], 1);
}

__global__ __launch_bounds__(1024) void k_scan1(const int* __restrict__ deg,
                                                int* __restrict__ tmp, int* __restrict__ bsum, int n) {
    __shared__ int wsum[16];
    int tid = threadIdx.x, lane = tid & 63, w = tid >> 6;
    int i = blockIdx.x * 1024 + tid;
    int v = (i < n) ? deg[i] + 1 : 0;   // +1 self loop
    int x = v;
    #pragma unroll
    for (int off = 1; off < 64; off <<= 1) {
        int t = __shfl_up(x, off);
        if (lane >= off) x += t;
    }
    if (lane == 63) wsum[w] = x;
    __syncthreads();
    int pre = 0;
    #pragma unroll
    for (int j = 0; j < 16; j++) if (j < w) pre += wsum[j];
    if (i < n) tmp[i] = pre + x - v;
    if (tid == 1023) bsum[blockIdx.x] = pre + x;
}

__global__ void k_scan2(const int* __restrict__ tmp, const int* __restrict__ bsum,
                        const float* __restrict__ a_s, const float* __restrict__ a_d,
                        int* __restrict__ offs, int* __restrict__ adj,
                        int* __restrict__ cursor, float* __restrict__ eb, int n, int nblk) {
    int i = blockIdx.x * 256 + threadIdx.x;
    if (i > n) return;
    int b = i >> 10;
    int pre = 0;
    for (int j = 0; j < b; j++) pre += bsum[j];
    if (i == n) {
        int tot = pre;
        for (int j = b; j < nblk; j++) tot += bsum[j];
        offs[n] = tot;
        return;
    }
    int o = pre + tmp[i];
    offs[i] = o;
    adj[o] = i;          // self loop first
    cursor[i] = o + 1;
    float4 s0 = *(const float4*)(a_s + (size_t)i * 8);
    float4 s1 = *(const float4*)(a_s + (size_t)i * 8 + 4);
    float4 d0 = *(const float4*)(a_d + (size_t)i * 8);
    float4 d1 = *(const float4*)(a_d + (size_t)i * 8 + 4);
    float4 e0, e1;
    e0.x = lrelu(s0.x + d0.x); e0.y = lrelu(s0.y + d0.y);
    e0.z = lrelu(s0.z + d0.z); e0.w = lrelu(s0.w + d0.w);
    e1.x = lrelu(s1.x + d1.x); e1.y = lrelu(s1.y + d1.y);
    e1.z = lrelu(s1.z + d1.z); e1.w = lrelu(s1.w + d1.w);
    *(float4*)(eb + (size_t)o * 8) = e0;
    *(float4*)(eb + (size_t)o * 8 + 4) = e1;
}

__global__ void k_fill_edge(const int* __restrict__ src, const int* __restrict__ dst,
                            const float* __restrict__ a_s, const float* __restrict__ a_d,
                            int* __restrict__ cursor, int* __restrict__ adj,
                            float* __restrict__ eb, int e) {
    int i = blockIdx.x * 256 + threadIdx.x;
    if (i >= e) return;
    int s = src[i], d = dst[i];
    int p = atomicAdd(&cursor[d], 1);
    adj[p] = s;
    float4 s0 = *(const float4*)(a_s + (size_t)s * 8);
    float4 s1 = *(const float4*)(a_s + (size_t)s * 8 + 4);
    float4 d0 = *(const float4*)(a_d + (size_t)d * 8);
    float4 d1 = *(const float4*)(a_d + (size_t)d * 8 + 4);
    float4 e0, e1;
    e0.x = lrelu(s0.x + d0.x); e0.y = lrelu(s0.y + d0.y);
    e0.z = lrelu(s0.z + d0.z); e0.w = lrelu(s0.w + d0.w);
    e1.x = lrelu(s1.x + d1.x); e1.y = lrelu(s1.y + d1.y);
    e1.z = lrelu(s1.z + d1.z); e1.w = lrelu(s1.w + d1.w);
    *(float4*)(eb + (size_t)p * 8) = e0;
    *(float4*)(eb + (size_t)p * 8 + 4) = e1;
}

// ---------------------------------------------------------------- GAT: softmax + aggregate h0 (1 wave/node)
// readlane (VALU) broadcasts instead of ds_bpermute — keeps LDS pipe idle
__global__ __launch_bounds__(256) void k_gat4(const int* __restrict__ offs, const int* __restrict__ adj,
                                              const float* __restrict__ eb,
                                              const float* __restrict__ h0,
                                              float* __restrict__ agg_pre, int n) {
    int lane = threadIdx.x & 63;
    int node = blockIdx.x * 4 + (threadIdx.x >> 6);
    if (node >= n) return;
    int beg = offs[node], end = offs[node + 1];
    int g = lane >> 3;

    // pass 1: online (m,s) per (g,h); coalesced eb reads
    float m = -1e30f, s = 0.f;
    for (int base = beg; base < end; base += 8) {
        if (base + g < end) {
            float ev = eb[(size_t)base * 8 + lane];
            if (ev > m) { s = s * __expf(m - ev) + 1.f; m = ev; }
            else        { s += __expf(ev - m); }
        }
    }
    #pragma unroll
    for (int off = 8; off < 64; off <<= 1) {
        float mo = __shfl_xor(m, off), so = __shfl_xor(s, off);
        float mn = fmaxf(m, mo);
        s = s * __expf(m - mn) + so * __expf(mo - mn);
        m = mn;
    }
    float rcp = 1.f / s;

    // pass 2: 64-edge superchunks; all broadcasts via v_readlane (SGPR), no LDS pipe
    float acc[8] = {0.f, 0.f, 0.f, 0.f, 0.f, 0.f, 0.f, 0.f};
    for (int sbase = beg; sbase < end; sbase += 64) {
        int scnt = end - sbase; if (scnt > 64) scnt = 64;
        int srcv = 0;
        if (lane < scnt) srcv = adj[sbase + lane];
        float al[8];
        #pragma unroll
        for (int j = 0; j < 8; j++) {
            int q = j * 8 + g;
            float ev = -1e30f;
            if (q < scnt) ev = eb[(size_t)sbase * 8 + j * 64 + lane];
            al[j] = __expf(ev - m) * rcp;   // 0 for padding slots
        }
        #pragma unroll
        for (int j = 0; j < 8; j++) {
            int qb = j * 8;
            if (qb >= scnt) break;
            int sg[8]; float xv[8];
            #pragma unroll
            for (int g2 = 0; g2 < 8; g2++)
                sg[g2] = __builtin_amdgcn_readlane(srcv, qb + g2);   // SGPR src index
            #pragma unroll
            for (int g2 = 0; g2 < 8; g2++)
                xv[g2] = h0[(size_t)sg[g2] * 64 + lane];             // SGPR-base + lane offset
            #pragma unroll
            for (int g2 = 0; g2 < 8; g2++) {
                #pragma unroll
                for (int h2 = 0; h2 < 8; h2++)
                    acc[h2] += rdlane(al[j], g2 * 8 + h2) * xv[g2];  // SGPR alpha operand
            }
        }
    }
    #pragma unroll
    for (int h2 = 0; h2 < 8; h2++)
        agg_pre[(size_t)node * 512 + h2 * 64 + lane] = acc[h2];
}

// ---------------------------------------------------------------- fused head-pair double GEMM -> partials
// 64-row tile, thread = 2 rows x 8 cols; As/Cs share one LDS buffer (33.8 KB total)
__global__ __launch_bounds__(256) void k_fused4(const float* __restrict__ agg_pre,
                                                const float* __restrict__ Wg,
                                                const float* __restrict__ bg,
                                                const float* __restrict__ Wh,
                                                float* __restrict__ part, int M) {
    __shared__ float AB[64 * 68];   // A for GEMM1, then C for GEMM2 (r-major, stride 68)
    __shared__ float Bs[64 * 64];   // Wg_h, then Wh_h (k-major)
    int tid = threadIdx.x;
    int r0 = blockIdx.x * 64;
    int tx = tid & 7;
    int ty = tid >> 3;
    int rr = tid >> 4, c4 = (tid & 15) * 4;
    float4 accO[2][2] = {};
    #pragma unroll
    for (int hh = 0; hh < 2; hh++) {
        int h = blockIdx.y * 2 + hh;
        #pragma unroll
        for (int pp = 0; pp < 4; pp++) {
            int r = rr + pp * 16;
            float4 av = make_float4(0.f, 0.f, 0.f, 0.f);
            if (r0 + r < M) av = *(const float4*)(agg_pre + (size_t)(r0 + r) * 512 + h * 64 + c4);
            *(float4*)&AB[r * 68 + c4] = av;
            *(float4*)&Bs[r * 64 + c4] = *(const float4*)(Wg + (size_t)r * 512 + h * 64 + c4);
        }
        __syncthreads();
        float4 acc1[2][2] = {};
        #pragma unroll 4
        for (int kc = 0; kc < 16; kc++) {
            float4 a0 = *(const float4*)&AB[(ty * 2 + 0) * 68 + kc * 4];
            float4 a1 = *(const float4*)&AB[(ty * 2 + 1) * 68 + kc * 4];
            #pragma unroll
            for (int kk = 0; kk < 4; kk++) {
                float ak0 = (&a0.x)[kk], ak1 = (&a1.x)[kk];
                float4 bL = *(const float4*)&Bs[(kc * 4 + kk) * 64 + tx * 8];
                float4 bH = *(const float4*)&Bs[(kc * 4 + kk) * 64 + tx * 8 + 4];
                acc1[0][0].x += ak0 * bL.x; acc1[0][0].y += ak0 * bL.y; acc1[0][0].z += ak0 * bL.z; acc1[0][0].w += ak0 * bL.w;
                acc1[0][1].x += ak0 * bH.x; acc1[0][1].y += ak0 * bH.y; acc1[0][1].z += ak0 * bH.z; acc1[0][1].w += ak0 * bH.w;
                acc1[1][0].x += ak1 * bL.x; acc1[1][0].y += ak1 * bL.y; acc1[1][0].z += ak1 * bL.z; acc1[1][0].w += ak1 * bL.w;
                acc1[1][1].x += ak1 * bH.x; acc1[1][1].y += ak1 * bH.y; acc1[1][1].z += ak1 * bH.z; acc1[1][1].w += ak1 * bH.w;
            }
        }
        __syncthreads();
        float4 bgL = *(const float4*)(bg + h * 64 + tx * 8);
        float4 bgH = *(const float4*)(bg + h * 64 + tx * 8 + 4);
        #pragma unroll
        for (int i = 0; i < 2; i++) {
            float4 cL, cH;
            cL.x = fmaxf(acc1[i][0].x + bgL.x, 0.f); cL.y = fmaxf(acc1[i][0].y + bgL.y, 0.f);
            cL.z = fmaxf(acc1[i][0].z + bgL.z, 0.f); cL.w = fmaxf(acc1[i][0].w + bgL.w, 0.f);
            cH.x = fmaxf(acc1[i][1].x + bgH.x, 0.f); cH.y = fmaxf(acc1[i][1].y + bgH.y, 0.f);
            cH.z = fmaxf(acc1[i][1].z + bgH.z, 0.f); cH.w = fmaxf(acc1[i][1].w + bgH.w, 0.f);
            *(float4*)&AB[(ty * 2 + i) * 68 + tx * 8] = cL;
            *(float4*)&AB[(ty * 2 + i) * 68 + tx * 8 + 4] = cH;
        }
        #pragma unroll
        for (int pp = 0; pp < 4; pp++) {
            int k = rr + pp * 16;
            *(float4*)&Bs[k * 64 + c4] = *(const float4*)(Wh + (size_t)(h * 64 + k) * 64 + c4);
        }
        __syncthreads();
        #pragma unroll 4
        for (int kc = 0; kc < 16; kc++) {
            float4 a0 = *(const float4*)&AB[(ty * 2 + 0) * 68 + kc * 4];
            float4 a1 = *(const float4*)&AB[(ty * 2 + 1) * 68 + kc * 4];
            #pragma unroll
            for (int kk = 0; kk < 4; kk++) {
                float ak0 = (&a0.x)[kk], ak1 = (&a1.x)[kk];
                float4 bL = *(const float4*)&Bs[(kc * 4 + kk) * 64 + tx * 8];
                float4 bH = *(const float4*)&Bs[(kc * 4 + kk) * 64 + tx * 8 + 4];
                accO[0][0].x += ak0 * bL.x; accO[0][0].y += ak0 * bL.y; accO[0][0].z += ak0 * bL.z; accO[0][0].w += ak0 * bL.w;
                accO[0][1].x += ak0 * bH.x; accO[0][1].y += ak0 * bH.y; accO[0][1].z += ak0 * bH.z; accO[0][1].w += ak0 * bH.w;
                accO[1][0].x += ak1 * bL.x; accO[1][0].y += ak1 * bL.y; accO[1][0].z += ak1 * bL.z; accO[1][0].w += ak1 * bL.w;
                accO[1][1].x += ak1 * bH.x; accO[1][1].y += ak1 * bH.y; accO[1][1].z += ak1 * bH.z; accO[1][1].w += ak1 * bH.w;
            }
        }
        __syncthreads();
    }
    float* Cb = part + (size_t)blockIdx.y * M * 64;
    #pragma unroll
    for (int i = 0; i < 2; i++) {
        int r = r0 + ty * 2 + i;
        if (r >= M) continue;
        *(float4*)(Cb + (size_t)r * 64 + tx * 8) = accO[i][0];
        *(float4*)(Cb + (size_t)r * 64 + tx * 8 + 4) = accO[i][1];
    }
}

// ---------------------------------------------------------------- Set2Set (3 iters) + final MLP; sums 4 partials + bh + relu on load
#define SROWS 208
__global__ __launch_bounds__(256) void k_s2s(const float* __restrict__ part,
                                             const float* __restrict__ bh,
                                             const int* __restrict__ segst,
                                             const float* __restrict__ W_ih, const float* __restrict__ W_hh,
                                             const float* __restrict__ b_ih, const float* __restrict__ b_hh,
                                             const float* __restrict__ W1, const float* __restrict__ b1,
                                             const float* __restrict__ W2, const float* __restrict__ b2,
                                             float* __restrict__ out, int M) {
    int b = blockIdx.x, tid = threadIdx.x, lane = tid & 63, w = tid >> 6;
    __shared__ float sc[SROWS * 65];
    __shared__ float wlds[1024];
    __shared__ float hl[64], cl[64], rl_[64];
    __shared__ float red[4];
    __shared__ float gsh[256];
    int beg = segst[b], end = segst[b + 1];
    int nrows = end - beg;
    int ncache = nrows < SROWS ? nrows : SROWS;
    const size_t PS = (size_t)M * 64;
    for (int idx = tid; idx < ncache * 16; idx += 256) {
        int r = idx >> 4, q = idx & 15;
        const float* pb = part + (size_t)(beg + r) * 64 + q * 4;
        float4 v0 = *(const float4*)pb;
        float4 v1 = *(const float4*)(pb + PS);
        float4 v2 = *(const float4*)(pb + 2 * PS);
        float4 v3 = *(const float4*)(pb + 3 * PS);
        float4 bv = *(const float4*)(bh + q * 4);
        float* p = &sc[r * 65 + q * 4];
        p[0] = fmaxf(v0.x + v1.x + v2.x + v3.x + bv.x, 0.f);
        p[1] = fmaxf(v0.y + v1.y + v2.y + v3.y + bv.y, 0.f);
        p[2] = fmaxf(v0.z + v1.z + v2.z + v3.z + bv.z, 0.f);
        p[3] = fmaxf(v0.w + v1.w + v2.w + v3.w + bv.w, 0.f);
    }
    if (tid < 64) { hl[tid] = 0.f; cl[tid] = 0.f; rl_[tid] = 0.f; }
    __syncthreads();

    for (int it = 0; it < 3; it++) {
        {
            float acc = b_ih[tid] + b_hh[tid];
            const float* wi = W_ih + (size_t)tid * 128;
            const float* wh = W_hh + (size_t)tid * 64;
            #pragma unroll 8
            for (int k = 0; k < 64; k++) acc += hl[k] * (wi[k] + wh[k]) + rl_[k] * wi[64 + k];
            gsh[tid] = acc;
        }
        __syncthreads();
        if (tid < 64) {
            float ig = gsh[tid], fg = gsh[64 + tid], gg = gsh[128 + tid], og = gsh[192 + tid];
            float cc = cl[tid];
            float si = 1.f / (1.f + __expf(-ig));
            float sf = 1.f / (1.f + __expf(-fg));
            float so = 1.f / (1.f + __expf(-og));
            float cn = sf * cc + si * tanhf(gg);
            cl[tid] = cn;
            hl[tid] = so * tanhf(cn);
        }
        __syncthreads();
        float ev[4];
        int nr = 0;
        float mloc = -1e30f;
        for (int i = tid; i < nrows; i += 256) {
            float d = 0.f;
            if (i < SROWS) {
                const float* rp = &sc[i * 65];
                #pragma unroll 16
                for (int j = 0; j < 64; j++) d += rp[j] * hl[j];
            } else {
                const float* pb = part + (size_t)(beg + i) * 64;
                for (int j = 0; j < 64; j++) {
                    float v = pb[j] + pb[PS + j] + pb[2 * PS + j] + pb[3 * PS + j] + bh[j];
                    d += fmaxf(v, 0.f) * hl[j];
                }
            }
            ev[nr++] = d;
            mloc = fmaxf(mloc, d);
        }
        #pragma unroll
        for (int off = 1; off < 64; off <<= 1) mloc = fmaxf(mloc, __shfl_xor(mloc, off));
        if (lane == 0) red[w] = mloc;
        __syncthreads();
        float m = fmaxf(fmaxf(red[0], red[1]), fmaxf(red[2], red[3]));
        __syncthreads();
        float sloc = 0.f;
        nr = 0;
        for (int i = tid; i < nrows; i += 256) {
            float wv = __expf(ev[nr++] - m);
            if (i < 1024) wlds[i] = wv;
            sloc += wv;
        }
        #pragma unroll
        for (int off = 1; off < 64; off <<= 1) sloc += __shfl_xor(sloc, off);
        if (lane == 0) red[w] = sloc;
        __syncthreads();
        float sv = red[0] + red[1] + red[2] + red[3];
        float inv = sv > 0.f ? 1.f / sv : 0.f;
        float acc = 0.f;
        for (int i = w; i < nrows; i += 4) {
            float v;
            if (i < SROWS) v = sc[i * 65 + lane];
            else {
                const float* pb = part + (size_t)(beg + i) * 64 + lane;
                v = fmaxf(pb[0] + pb[PS] + pb[2 * PS] + pb[3 * PS] + bh[lane], 0.f);
            }
            acc += wlds[i] * v;
        }
        gsh[w * 64 + lane] = acc;
        __syncthreads();
        if (tid < 64)
            rl_[tid] = (gsh[tid] + gsh[64 + tid] + gsh[128 + tid] + gsh[192 + tid]) * inv;
        __syncthreads();
    }
    if (tid < 64) {
        float t = b1[tid];
        #pragma unroll 8
        for (int k = 0; k < 64; k++)
            t += hl[k] * W1[(size_t)k * 64 + tid] + rl_[k] * W1[(size_t)(64 + k) * 64 + tid];
        t = fmaxf(t, 0.f) * W2[tid];
        #pragma unroll
        for (int off = 32; off > 0; off >>= 1) t += __shfl_xor(t, off);
        if (tid == 0) out[b] = t + b2[0];
    }
}

// ----------------------------------------------------------------
extern "C" void kernel_launch(void* const* d_in, const int* in_sizes, int n_in,
                              void* d_out, int out_size, void* d_ws, size_t ws_size,
                              hipStream_t stream) {
    const float* x     = (const float*)d_in[0];
    const int*   ei    = (const int*)d_in[1];
    const int*   batch = (const int*)d_in[2];
    const float* W0    = (const float*)d_in[3];
    const float* b0    = (const float*)d_in[4];
    const float* Wg    = (const float*)d_in[5];
    const float* att_s = (const float*)d_in[6];
    const float* att_d = (const float*)d_in[7];
    const float* bg    = (const float*)d_in[8];
    const float* Wh    = (const float*)d_in[9];
    const float* bh    = (const float*)d_in[10];
    const float* W_ih  = (const float*)d_in[11];
    const float* W_hh  = (const float*)d_in[12];
    const float* b_ih  = (const float*)d_in[13];
    const float* b_hh  = (const float*)d_in[14];
    const float* W1    = (const float*)d_in[15];
    const float* b1    = (const float*)d_in[16];
    const float* W2    = (const float*)d_in[17];
    const float* b2    = (const float*)d_in[18];
    float* out = (float*)d_out;

    const int* esrc = ei;
    const int* edst = ei + N_EDGES;

    char* wsb = (char*)d_ws;
    size_t off = 0;
    auto alloc = [&](size_t bytes) {
        void* p = wsb + off;
        off = (off + bytes + 255) & ~(size_t)255;
        return p;
    };
    float* h0      = (float*)alloc((size_t)N_NODES * 64 * 4);
    float* agg_pre = (float*)alloc((size_t)N_NODES * 512 * 4);
    float* part    = (float*)alloc((size_t)4 * N_NODES * 64 * 4);
    float* a_s     = (float*)alloc((size_t)N_NODES * 8 * 4);
    float* a_d     = (float*)alloc((size_t)N_NODES * 8 * 4);
    float* vsd     = (float*)alloc(64 * 16 * 4);
    float* eb      = (float*)alloc((size_t)(N_EDGES + N_NODES) * 8 * 4);
    int*   deg     = (int*)alloc((size_t)N_NODES * 4);
    int*   tmp     = (int*)alloc((size_t)N_NODES * 4);
    int*   bsum    = (int*)alloc(32 * 4);
    int*   offs    = (int*)alloc((size_t)(N_NODES + 1) * 4);
    int*   cursor  = (int*)alloc((size_t)N_NODES * 4);
    int*   adj     = (int*)alloc((size_t)(N_EDGES + N_NODES) * 4);
    int*   segst   = (int*)alloc((size_t)(NBATCH + 1) * 4);

    // node MLP (+zero deg), tiny setup (vsd + bounds), attention dots
    k_h0<<<(N_NODES + 3) / 4, 256, 0, stream>>>(x, W0, b0, h0, deg, N_NODES);
    k_small<<<2, 512, 0, stream>>>(Wg, att_s, att_d, vsd, batch, segst, N_NODES, NBATCH);
    k_asd<<<N_NODES / 16, 256, 0, stream>>>(h0, vsd, a_s, a_d);

    // CSR by dst (with self loops) + per-position logits
    k_count<<<(N_EDGES + 255) / 256, 256, 0, stream>>>(edst, deg, N_EDGES);
    const int nblk = (N_NODES + 1023) / 1024;
    k_scan1<<<nblk, 1024, 0, stream>>>(deg, tmp, bsum, N_NODES);
    k_scan2<<<(N_NODES + 256) / 256, 256, 0, stream>>>(tmp, bsum, a_s, a_d, offs, adj, cursor, eb, N_NODES, nblk);
    k_fill_edge<<<(N_EDGES + 255) / 256, 256, 0, stream>>>(esrc, edst, a_s, a_d, cursor, adj, eb, N_EDGES);

    // GAT aggregate + fused 64-row head-pair double-GEMM (partials)
    k_gat4<<<(N_NODES + 3) / 4, 256, 0, stream>>>(offs, adj, eb, h0, agg_pre, N_NODES);
    k_fused4<<<dim3((N_NODES + 63) / 64, 4), 256, 0, stream>>>(agg_pre, Wg, bg, Wh, part, N_NODES);

    // Set2Set (3 iters) + final MLP, one kernel (sums partials on load)
    k_s2s<<<NBATCH, 256, 0, stream>>>(part, bh, segst, W_ih, W_hh, b_ih, b_hh, W1, b1, W2, b2, out, N_NODES);
}

// Round 10
// 256.644 us; speedup vs baseline: 1.2096x; 1.0491x over previous
//
#include <hip/hip_runtime.h>

#define N_NODES 20000
#define N_EDGES 320000
#define NBATCH  128

__device__ __forceinline__ float lrelu(float v) { return v > 0.f ? v : 0.2f * v; }
__device__ __forceinline__ float rdlane(float v, int l) {
    return __int_as_float(__builtin_amdgcn_readlane(__float_as_int(v), l));
}

// ---------------------------------------------------------------- setup: vsd + segment bounds + zero deg
// grid 82 x 256: blocks 0,1 -> vsd; block 2 -> segst; all blocks zero a deg slice
__global__ void k_small(const float* __restrict__ Wg, const float* __restrict__ att_s,
                        const float* __restrict__ att_d, float* __restrict__ vsd,
                        const int* __restrict__ batch, int* __restrict__ segst,
                        int* __restrict__ deg, int n, int b) {
    int tid = threadIdx.x;
    int gid = blockIdx.x * 256 + tid;
    if (gid < n) deg[gid] = 0;
    if (blockIdx.x < 2) {
        int t = blockIdx.x * 256 + tid;   // 0..511
        int k = t >> 3, h = t & 7;
        const float* wrow = Wg + (size_t)k * 512 + h * 64;
        float s1 = 0.f, s2 = 0.f;
        #pragma unroll 8
        for (int c = 0; c < 64; c++) {
            float w = wrow[c];
            s1 += w * att_s[h * 64 + c];
            s2 += w * att_d[h * 64 + c];
        }
        vsd[k * 16 + h] = s1;
        vsd[k * 16 + 8 + h] = s2;
    } else if (blockIdx.x == 2) {
        if (tid > b) return;
        int lo = 0, hi = n;
        while (lo < hi) { int mid = (lo + hi) >> 1; if (batch[mid] < tid) lo = mid + 1; else hi = mid; }
        segst[tid] = lo;
    }
}

// ---------------------------------------------------------------- h0 = relu(x@W0+b0) + edge degree count
__global__ void k_h0c(const float* __restrict__ x, const float* __restrict__ W0,
                      const float* __restrict__ b0, float* __restrict__ h0,
                      const int* __restrict__ edst, int* __restrict__ deg, int n) {
    __shared__ float ws[25 * 64];
    __shared__ float bs[64];
    __shared__ float xs[100];
    int t = threadIdx.x;
    // 64 edge-count atomics per block (5000 blocks x 64 = 320000), fire-and-forget
    if (t < 64) {
        int e = blockIdx.x * 64 + t;
        atomicAdd(&deg[edst[e]], 1);
    }
    for (int i = t; i < 25 * 64; i += 256) ws[i] = W0[i];
    if (t < 64) bs[t] = b0[t];
    int nb = blockIdx.x * 4;
    if (t < 100 && nb * 25 + t < n * 25) xs[t] = x[(size_t)nb * 25 + t];
    __syncthreads();
    int node = nb + (t >> 6);
    int c = t & 63;
    if (node >= n) return;
    float s = bs[c];
    const float* xr = xs + (t >> 6) * 25;
    #pragma unroll
    for (int k = 0; k < 25; k++) s += xr[k] * ws[k * 64 + c];
    h0[(size_t)node * 64 + c] = fmaxf(s, 0.f);
}

// ---------------------------------------------------------------- [a_s|a_d] = h0 @ vsd  +  local scan (blocks >= nasd)
__global__ __launch_bounds__(256) void k_asd_scan(const float* __restrict__ h0,
                                                  const float* __restrict__ vsd,
                                                  float* __restrict__ a_s, float* __restrict__ a_d,
                                                  const int* __restrict__ deg,
                                                  int* __restrict__ tmp, int* __restrict__ bsum,
                                                  int nasd, int n) {
    __shared__ float hs[16][65];
    __shared__ float vl[64 * 16];
    __shared__ int wsum[4];
    int tid = threadIdx.x;
    if (blockIdx.x >= nasd) {
        // local inclusive scan of (deg[i]+1) over a 256-chunk
        int s = blockIdx.x - nasd;
        int i = s * 256 + tid;
        int lane = tid & 63, w = tid >> 6;
        int v = (i < n) ? deg[i] + 1 : 0;   // +1 self loop
        int x = v;
        #pragma unroll
        for (int off = 1; off < 64; off <<= 1) {
            int t2 = __shfl_up(x, off);
            if (lane >= off) x += t2;
        }
        if (lane == 63) wsum[w] = x;
        __syncthreads();
        int pre = 0;
        #pragma unroll
        for (int j = 0; j < 4; j++) if (j < w) pre += wsum[j];
        if (i < n) tmp[i] = pre + x - v;    // block-local exclusive
        if (tid == 255) bsum[s] = pre + x;
        return;
    }
    int rbase = blockIdx.x * 16;
    {
        int row = tid / 16, c4 = (tid % 16) * 4;
        float4 hv = *(const float4*)(h0 + (size_t)(rbase + row) * 64 + c4);
        hs[row][c4] = hv.x; hs[row][c4 + 1] = hv.y; hs[row][c4 + 2] = hv.z; hs[row][c4 + 3] = hv.w;
    }
    #pragma unroll
    for (int j = 0; j < 4; j++) vl[tid + j * 256] = vsd[tid + j * 256];
    __syncthreads();
    int nl = tid / 16, o = tid % 16;
    float acc = 0.f;
    #pragma unroll 16
    for (int k = 0; k < 64; k++) acc += hs[nl][k] * vl[k * 16 + o];
    int node = rbase + nl;
    if (o < 8) a_s[node * 8 + o] = acc;
    else       a_d[node * 8 + (o - 8)] = acc;
}

// ---------------------------------------------------------------- scan2: global offsets + self loop + self logits
__global__ void k_scan2(const int* __restrict__ tmp, const int* __restrict__ bsum,
                        const float* __restrict__ a_s, const float* __restrict__ a_d,
                        int* __restrict__ offs, int* __restrict__ adj,
                        int* __restrict__ cursor, float* __restrict__ eb, int n, int nblk) {
    int i = blockIdx.x * 256 + threadIdx.x;
    if (i > n) return;
    int b = i >> 8;                 // 256-sized scan chunks
    int pre = 0;
    for (int j = 0; j < b; j++) pre += bsum[j];
    if (i == n) {
        int tot = pre;
        for (int j = b; j < nblk; j++) tot += bsum[j];
        offs[n] = tot;
        return;
    }
    int o = pre + tmp[i];
    offs[i] = o;
    adj[o] = i;          // self loop first
    cursor[i] = o + 1;
    float4 s0 = *(const float4*)(a_s + (size_t)i * 8);
    float4 s1 = *(const float4*)(a_s + (size_t)i * 8 + 4);
    float4 d0 = *(const float4*)(a_d + (size_t)i * 8);
    float4 d1 = *(const float4*)(a_d + (size_t)i * 8 + 4);
    float4 e0, e1;
    e0.x = lrelu(s0.x + d0.x); e0.y = lrelu(s0.y + d0.y);
    e0.z = lrelu(s0.z + d0.z); e0.w = lrelu(s0.w + d0.w);
    e1.x = lrelu(s1.x + d1.x); e1.y = lrelu(s1.y + d1.y);
    e1.z = lrelu(s1.z + d1.z); e1.w = lrelu(s1.w + d1.w);
    *(float4*)(eb + (size_t)o * 8) = e0;
    *(float4*)(eb + (size_t)o * 8 + 4) = e1;
}

__global__ void k_fill_edge(const int* __restrict__ src, const int* __restrict__ dst,
                            const float* __restrict__ a_s, const float* __restrict__ a_d,
                            int* __restrict__ cursor, int* __restrict__ adj,
                            float* __restrict__ eb, int e) {
    int i = blockIdx.x * 256 + threadIdx.x;
    if (i >= e) return;
    int s = src[i], d = dst[i];
    int p = atomicAdd(&cursor[d], 1);
    adj[p] = s;
    float4 s0 = *(const float4*)(a_s + (size_t)s * 8);
    float4 s1 = *(const float4*)(a_s + (size_t)s * 8 + 4);
    float4 d0 = *(const float4*)(a_d + (size_t)d * 8);
    float4 d1 = *(const float4*)(a_d + (size_t)d * 8 + 4);
    float4 e0, e1;
    e0.x = lrelu(s0.x + d0.x); e0.y = lrelu(s0.y + d0.y);
    e0.z = lrelu(s0.z + d0.z); e0.w = lrelu(s0.w + d0.w);
    e1.x = lrelu(s1.x + d1.x); e1.y = lrelu(s1.y + d1.y);
    e1.z = lrelu(s1.z + d1.z); e1.w = lrelu(s1.w + d1.w);
    *(float4*)(eb + (size_t)p * 8) = e0;
    *(float4*)(eb + (size_t)p * 8 + 4) = e1;
}

// ---------------------------------------------------------------- GAT: softmax + aggregate h0 (1 wave/node)
// readlane broadcasts; 2-group gather unroll (16 loads in flight)
__global__ __launch_bounds__(256) void k_gat5(const int* __restrict__ offs, const int* __restrict__ adj,
                                              const float* __restrict__ eb,
                                              const float* __restrict__ h0,
                                              float* __restrict__ agg_pre, int n) {
    int lane = threadIdx.x & 63;
    int node = blockIdx.x * 4 + (threadIdx.x >> 6);
    if (node >= n) return;
    int beg = offs[node], end = offs[node + 1];
    int g = lane >> 3;

    // pass 1: online (m,s) per (g,h); coalesced eb reads
    float m = -1e30f, s = 0.f;
    for (int base = beg; base < end; base += 8) {
        if (base + g < end) {
            float ev = eb[(size_t)base * 8 + lane];
            if (ev > m) { s = s * __expf(m - ev) + 1.f; m = ev; }
            else        { s += __expf(ev - m); }
        }
    }
    #pragma unroll
    for (int off = 8; off < 64; off <<= 1) {
        float mo = __shfl_xor(m, off), so = __shfl_xor(s, off);
        float mn = fmaxf(m, mo);
        s = s * __expf(m - mn) + so * __expf(mo - mn);
        m = mn;
    }
    float rcp = 1.f / s;

    // pass 2: 64-edge superchunks; readlane broadcasts; 16 gathers in flight
    float acc[8] = {0.f, 0.f, 0.f, 0.f, 0.f, 0.f, 0.f, 0.f};
    for (int sbase = beg; sbase < end; sbase += 64) {
        int scnt = end - sbase; if (scnt > 64) scnt = 64;
        int srcv = 0;
        if (lane < scnt) srcv = adj[sbase + lane];
        float al[8];
        #pragma unroll
        for (int j = 0; j < 8; j++) {
            int q = j * 8 + g;
            float ev = -1e30f;
            if (q < scnt) ev = eb[(size_t)sbase * 8 + j * 64 + lane];
            al[j] = __expf(ev - m) * rcp;   // 0 for padding slots
        }
        #pragma unroll
        for (int j = 0; j < 8; j += 2) {
            int qb0 = j * 8, qb1 = (j + 1) * 8;
            if (qb0 >= scnt) break;
            bool has1 = qb1 < scnt;
            int sg0[8], sg1[8];
            float xv0[8], xv1[8];
            #pragma unroll
            for (int g2 = 0; g2 < 8; g2++) sg0[g2] = __builtin_amdgcn_readlane(srcv, qb0 + g2);
            #pragma unroll
            for (int g2 = 0; g2 < 8; g2++) sg1[g2] = __builtin_amdgcn_readlane(srcv, qb1 + g2);
            #pragma unroll
            for (int g2 = 0; g2 < 8; g2++) xv0[g2] = h0[(size_t)sg0[g2] * 64 + lane];
            if (has1) {
                #pragma unroll
                for (int g2 = 0; g2 < 8; g2++) xv1[g2] = h0[(size_t)sg1[g2] * 64 + lane];
            }
            #pragma unroll
            for (int g2 = 0; g2 < 8; g2++) {
                #pragma unroll
                for (int h2 = 0; h2 < 8; h2++)
                    acc[h2] += rdlane(al[j], g2 * 8 + h2) * xv0[g2];
            }
            if (has1) {
                #pragma unroll
                for (int g2 = 0; g2 < 8; g2++) {
                    #pragma unroll
                    for (int h2 = 0; h2 < 8; h2++)
                        acc[h2] += rdlane(al[j + 1], g2 * 8 + h2) * xv1[g2];
                }
            }
        }
    }
    #pragma unroll
    for (int h2 = 0; h2 < 8; h2++)
        agg_pre[(size_t)node * 512 + h2 * 64 + lane] = acc[h2];
}

// ---------------------------------------------------------------- fused head-pair double GEMM -> partials
__global__ __launch_bounds__(256) void k_fused4(const float* __restrict__ agg_pre,
                                                const float* __restrict__ Wg,
                                                const float* __restrict__ bg,
                                                const float* __restrict__ Wh,
                                                float* __restrict__ part, int M) {
    __shared__ float AB[64 * 68];   // A for GEMM1, then C for GEMM2 (r-major, stride 68)
    __shared__ float Bs[64 * 64];   // Wg_h, then Wh_h (k-major)
    int tid = threadIdx.x;
    int r0 = blockIdx.x * 64;
    int tx = tid & 7;
    int ty = tid >> 3;
    int rr = tid >> 4, c4 = (tid & 15) * 4;
    float4 accO[2][2] = {};
    #pragma unroll
    for (int hh = 0; hh < 2; hh++) {
        int h = blockIdx.y * 2 + hh;
        #pragma unroll
        for (int pp = 0; pp < 4; pp++) {
            int r = rr + pp * 16;
            float4 av = make_float4(0.f, 0.f, 0.f, 0.f);
            if (r0 + r < M) av = *(const float4*)(agg_pre + (size_t)(r0 + r) * 512 + h * 64 + c4);
            *(float4*)&AB[r * 68 + c4] = av;
            *(float4*)&Bs[r * 64 + c4] = *(const float4*)(Wg + (size_t)r * 512 + h * 64 + c4);
        }
        __syncthreads();
        float4 acc1[2][2] = {};
        #pragma unroll 4
        for (int kc = 0; kc < 16; kc++) {
            float4 a0 = *(const float4*)&AB[(ty * 2 + 0) * 68 + kc * 4];
            float4 a1 = *(const float4*)&AB[(ty * 2 + 1) * 68 + kc * 4];
            #pragma unroll
            for (int kk = 0; kk < 4; kk++) {
                float ak0 = (&a0.x)[kk], ak1 = (&a1.x)[kk];
                float4 bL = *(const float4*)&Bs[(kc * 4 + kk) * 64 + tx * 8];
                float4 bH = *(const float4*)&Bs[(kc * 4 + kk) * 64 + tx * 8 + 4];
                acc1[0][0].x += ak0 * bL.x; acc1[0][0].y += ak0 * bL.y; acc1[0][0].z += ak0 * bL.z; acc1[0][0].w += ak0 * bL.w;
                acc1[0][1].x += ak0 * bH.x; acc1[0][1].y += ak0 * bH.y; acc1[0][1].z += ak0 * bH.z; acc1[0][1].w += ak0 * bH.w;
                acc1[1][0].x += ak1 * bL.x; acc1[1][0].y += ak1 * bL.y; acc1[1][0].z += ak1 * bL.z; acc1[1][0].w += ak1 * bL.w;
                acc1[1][1].x += ak1 * bH.x; acc1[1][1].y += ak1 * bH.y; acc1[1][1].z += ak1 * bH.z; acc1[1][1].w += ak1 * bH.w;
            }
        }
        __syncthreads();
        float4 bgL = *(const float4*)(bg + h * 64 + tx * 8);
        float4 bgH = *(const float4*)(bg + h * 64 + tx * 8 + 4);
        #pragma unroll
        for (int i = 0; i < 2; i++) {
            float4 cL, cH;
            cL.x = fmaxf(acc1[i][0].x + bgL.x, 0.f); cL.y = fmaxf(acc1[i][0].y + bgL.y, 0.f);
            cL.z = fmaxf(acc1[i][0].z + bgL.z, 0.f); cL.w = fmaxf(acc1[i][0].w + bgL.w, 0.f);
            cH.x = fmaxf(acc1[i][1].x + bgH.x, 0.f); cH.y = fmaxf(acc1[i][1].y + bgH.y, 0.f);
            cH.z = fmaxf(acc1[i][1].z + bgH.z, 0.f); cH.w = fmaxf(acc1[i][1].w + bgH.w, 0.f);
            *(float4*)&AB[(ty * 2 + i) * 68 + tx * 8] = cL;
            *(float4*)&AB[(ty * 2 + i) * 68 + tx * 8 + 4] = cH;
        }
        #pragma unroll
        for (int pp = 0; pp < 4; pp++) {
            int k = rr + pp * 16;
            *(float4*)&Bs[k * 64 + c4] = *(const float4*)(Wh + (size_t)(h * 64 + k) * 64 + c4);
        }
        __syncthreads();
        #pragma unroll 4
        for (int kc = 0; kc < 16; kc++) {
            float4 a0 = *(const float4*)&AB[(ty * 2 + 0) * 68 + kc * 4];
            float4 a1 = *(const float4*)&AB[(ty * 2 + 1) * 68 + kc * 4];
            #pragma unroll
            for (int kk = 0; kk < 4; kk++) {
                float ak0 = (&a0.x)[kk], ak1 = (&a1.x)[kk];
                float4 bL = *(const float4*)&Bs[(kc * 4 + kk) * 64 + tx * 8];
                float4 bH = *(const float4*)&Bs[(kc * 4 + kk) * 64 + tx * 8 + 4];
                accO[0][0].x += ak0 * bL.x; accO[0][0].y += ak0 * bL.y; accO[0][0].z += ak0 * bL.z; accO[0][0].w += ak0 * bL.w;
                accO[0][1].x += ak0 * bH.x; accO[0][1].y += ak0 * bH.y; accO[0][1].z += ak0 * bH.z; accO[0][1].w += ak0 * bH.w;
                accO[1][0].x += ak1 * bL.x; accO[1][0].y += ak1 * bL.y; accO[1][0].z += ak1 * bL.z; accO[1][0].w += ak1 * bL.w;
                accO[1][1].x += ak1 * bH.x; accO[1][1].y += ak1 * bH.y; accO[1][1].z += ak1 * bH.z; accO[1][1].w += ak1 * bH.w;
            }
        }
        __syncthreads();
    }
    float* Cb = part + (size_t)blockIdx.y * M * 64;
    #pragma unroll
    for (int i = 0; i < 2; i++) {
        int r = r0 + ty * 2 + i;
        if (r >= M) continue;
        *(float4*)(Cb + (size_t)r * 64 + tx * 8) = accO[i][0];
        *(float4*)(Cb + (size_t)r * 64 + tx * 8 + 4) = accO[i][1];
    }
}

// ---------------------------------------------------------------- Set2Set (3 iters) + final MLP; sums 4 partials + bh + relu on load
#define SROWS 208
__global__ __launch_bounds__(256) void k_s2s(const float* __restrict__ part,
                                             const float* __restrict__ bh,
                                             const int* __restrict__ segst,
                                             const float* __restrict__ W_ih, const float* __restrict__ W_hh,
                                             const float* __restrict__ b_ih, const float* __restrict__ b_hh,
                                             const float* __restrict__ W1, const float* __restrict__ b1,
                                             const float* __restrict__ W2, const float* __restrict__ b2,
                                             float* __restrict__ out, int M) {
    int b = blockIdx.x, tid = threadIdx.x, lane = tid & 63, w = tid >> 6;
    __shared__ float sc[SROWS * 65];
    __shared__ float wlds[1024];
    __shared__ float hl[64], cl[64], rl_[64];
    __shared__ float red[4];
    __shared__ float gsh[256];
    int beg = segst[b], end = segst[b + 1];
    int nrows = end - beg;
    int ncache = nrows < SROWS ? nrows : SROWS;
    const size_t PS = (size_t)M * 64;
    for (int idx = tid; idx < ncache * 16; idx += 256) {
        int r = idx >> 4, q = idx & 15;
        const float* pb = part + (size_t)(beg + r) * 64 + q * 4;
        float4 v0 = *(const float4*)pb;
        float4 v1 = *(const float4*)(pb + PS);
        float4 v2 = *(const float4*)(pb + 2 * PS);
        float4 v3 = *(const float4*)(pb + 3 * PS);
        float4 bv = *(const float4*)(bh + q * 4);
        float* p = &sc[r * 65 + q * 4];
        p[0] = fmaxf(v0.x + v1.x + v2.x + v3.x + bv.x, 0.f);
        p[1] = fmaxf(v0.y + v1.y + v2.y + v3.y + bv.y, 0.f);
        p[2] = fmaxf(v0.z + v1.z + v2.z + v3.z + bv.z, 0.f);
        p[3] = fmaxf(v0.w + v1.w + v2.w + v3.w + bv.w, 0.f);
    }
    if (tid < 64) { hl[tid] = 0.f; cl[tid] = 0.f; rl_[tid] = 0.f; }
    __syncthreads();

    for (int it = 0; it < 3; it++) {
        {
            float acc = b_ih[tid] + b_hh[tid];
            const float* wi = W_ih + (size_t)tid * 128;
            const float* wh = W_hh + (size_t)tid * 64;
            #pragma unroll 8
            for (int k = 0; k < 64; k++) acc += hl[k] * (wi[k] + wh[k]) + rl_[k] * wi[64 + k];
            gsh[tid] = acc;
        }
        __syncthreads();
        if (tid < 64) {
            float ig = gsh[tid], fg = gsh[64 + tid], gg = gsh[128 + tid], og = gsh[192 + tid];
            float cc = cl[tid];
            float si = 1.f / (1.f + __expf(-ig));
            float sf = 1.f / (1.f + __expf(-fg));
            float so = 1.f / (1.f + __expf(-og));
            float cn = sf * cc + si * tanhf(gg);
            cl[tid] = cn;
            hl[tid] = so * tanhf(cn);
        }
        __syncthreads();
        float ev[4];
        int nr = 0;
        float mloc = -1e30f;
        for (int i = tid; i < nrows; i += 256) {
            float d = 0.f;
            if (i < SROWS) {
                const float* rp = &sc[i * 65];
                #pragma unroll 16
                for (int j = 0; j < 64; j++) d += rp[j] * hl[j];
            } else {
                const float* pb = part + (size_t)(beg + i) * 64;
                for (int j = 0; j < 64; j++) {
                    float v = pb[j] + pb[PS + j] + pb[2 * PS + j] + pb[3 * PS + j] + bh[j];
                    d += fmaxf(v, 0.f) * hl[j];
                }
            }
            ev[nr++] = d;
            mloc = fmaxf(mloc, d);
        }
        #pragma unroll
        for (int off = 1; off < 64; off <<= 1) mloc = fmaxf(mloc, __shfl_xor(mloc, off));
        if (lane == 0) red[w] = mloc;
        __syncthreads();
        float m = fmaxf(fmaxf(red[0], red[1]), fmaxf(red[2], red[3]));
        __syncthreads();
        float sloc = 0.f;
        nr = 0;
        for (int i = tid; i < nrows; i += 256) {
            float wv = __expf(ev[nr++] - m);
            if (i < 1024) wlds[i] = wv;
            sloc += wv;
        }
        #pragma unroll
        for (int off = 1; off < 64; off <<= 1) sloc += __shfl_xor(sloc, off);
        if (lane == 0) red[w] = sloc;
        __syncthreads();
        float sv = red[0] + red[1] + red[2] + red[3];
        float inv = sv > 0.f ? 1.f / sv : 0.f;
        float acc = 0.f;
        for (int i = w; i < nrows; i += 4) {
            float v;
            if (i < SROWS) v = sc[i * 65 + lane];
            else {
                const float* pb = part + (size_t)(beg + i) * 64 + lane;
                v = fmaxf(pb[0] + pb[PS] + pb[2 * PS] + pb[3 * PS] + bh[lane], 0.f);
            }
            acc += wlds[i] * v;
        }
        gsh[w * 64 + lane] = acc;
        __syncthreads();
        if (tid < 64)
            rl_[tid] = (gsh[tid] + gsh[64 + tid] + gsh[128 + tid] + gsh[192 + tid]) * inv;
        __syncthreads();
    }
    if (tid < 64) {
        float t = b1[tid];
        #pragma unroll 8
        for (int k = 0; k < 64; k++)
            t += hl[k] * W1[(size_t)k * 64 + tid] + rl_[k] * W1[(size_t)(64 + k) * 64 + tid];
        t = fmaxf(t, 0.f) * W2[tid];
        #pragma unroll
        for (int off = 32; off > 0; off >>= 1) t += __shfl_xor(t, off);
        if (tid == 0) out[b] = t + b2[0];
    }
}

// ----------------------------------------------------------------
extern "C" void kernel_launch(void* const* d_in, const int* in_sizes, int n_in,
                              void* d_out, int out_size, void* d_ws, size_t ws_size,
                              hipStream_t stream) {
    const float* x     = (const float*)d_in[0];
    const int*   ei    = (const int*)d_in[1];
    const int*   batch = (const int*)d_in[2];
    const float* W0    = (const float*)d_in[3];
    const float* b0    = (const float*)d_in[4];
    const float* Wg    = (const float*)d_in[5];
    const float* att_s = (const float*)d_in[6];
    const float* att_d = (const float*)d_in[7];
    const float* bg    = (const float*)d_in[8];
    const float* Wh    = (const float*)d_in[9];
    const float* bh    = (const float*)d_in[10];
    const float* W_ih  = (const float*)d_in[11];
    const float* W_hh  = (const float*)d_in[12];
    const float* b_ih  = (const float*)d_in[13];
    const float* b_hh  = (const float*)d_in[14];
    const float* W1    = (const float*)d_in[15];
    const float* b1    = (const float*)d_in[16];
    const float* W2    = (const float*)d_in[17];
    const float* b2    = (const float*)d_in[18];
    float* out = (float*)d_out;

    const int* esrc = ei;
    const int* edst = ei + N_EDGES;

    char* wsb = (char*)d_ws;
    size_t off = 0;
    auto alloc = [&](size_t bytes) {
        void* p = wsb + off;
        off = (off + bytes + 255) & ~(size_t)255;
        return p;
    };
    float* h0      = (float*)alloc((size_t)N_NODES * 64 * 4);
    float* agg_pre = (float*)alloc((size_t)N_NODES * 512 * 4);
    float* part    = (float*)alloc((size_t)4 * N_NODES * 64 * 4);
    float* a_s     = (float*)alloc((size_t)N_NODES * 8 * 4);
    float* a_d     = (float*)alloc((size_t)N_NODES * 8 * 4);
    float* vsd     = (float*)alloc(64 * 16 * 4);
    float* eb      = (float*)alloc((size_t)(N_EDGES + N_NODES) * 8 * 4);
    int*   deg     = (int*)alloc((size_t)N_NODES * 4);
    int*   tmp     = (int*)alloc((size_t)N_NODES * 4);
    int*   bsum    = (int*)alloc(128 * 4);
    int*   offs    = (int*)alloc((size_t)(N_NODES + 1) * 4);
    int*   cursor  = (int*)alloc((size_t)N_NODES * 4);
    int*   adj     = (int*)alloc((size_t)(N_EDGES + N_NODES) * 4);
    int*   segst   = (int*)alloc((size_t)(NBATCH + 1) * 4);

    const int nscan = (N_NODES + 255) / 256;    // 79
    const int nasd  = N_NODES / 16;             // 1250

    // setup (zero deg + vsd + segst) -> node MLP + edge count -> attn dots + local scan
    k_small<<<82, 256, 0, stream>>>(Wg, att_s, att_d, vsd, batch, segst, deg, N_NODES, NBATCH);
    k_h0c<<<N_NODES / 4, 256, 0, stream>>>(x, W0, b0, h0, edst, deg, N_NODES);
    k_asd_scan<<<nasd + nscan, 256, 0, stream>>>(h0, vsd, a_s, a_d, deg, tmp, bsum, nasd, N_NODES);

    // global offsets + self loops + edge fill (with logits)
    k_scan2<<<(N_NODES + 256) / 256, 256, 0, stream>>>(tmp, bsum, a_s, a_d, offs, adj, cursor, eb, N_NODES, nscan);
    k_fill_edge<<<(N_EDGES + 255) / 256, 256, 0, stream>>>(esrc, edst, a_s, a_d, cursor, adj, eb, N_EDGES);

    // GAT aggregate + fused 64-row head-pair double-GEMM (partials)
    k_gat5<<<(N_NODES + 3) / 4, 256, 0, stream>>>(offs, adj, eb, h0, agg_pre, N_NODES);
    k_fused4<<<dim3((N_NODES + 63) / 64, 4), 256, 0, stream>>>(agg_pre, Wg, bg, Wh, part, N_NODES);

    // Set2Set (3 iters) + final MLP, one kernel (sums partials on load)
    k_s2s<<<NBATCH, 256, 0, stream>>>(part, bh, segst, W_ih, W_hh, b_ih, b_hh, W1, b1, W2, b2, out, N_NODES);
}